// Round 1
// baseline (550.618 us; speedup 1.0000x reference)
//
#include <hip/hip_runtime.h>
#include <hip/hip_bf16.h>
#include <math.h>

#define BDIM 1024
#define HEADS 16
#define HDIM 64
#define LSEQ 2048
#define NBATCH 2
#define DFFDIM 4096

typedef __bf16 bf16x8_t __attribute__((ext_vector_type(8)));
typedef float f32x4_t __attribute__((ext_vector_type(4)));

__device__ __forceinline__ ushort f2bf(float f) {
    union { __hip_bfloat16 b; ushort u; } cv;
    cv.b = __float2bfloat16(f);
    return cv.u;
}

// ---------------- transpose + fp32->bf16 convert: Wt[n][k] = bf16(W[k][n]) ----
__global__ __launch_bounds__(256) void transpose_cvt(const float* __restrict__ W,
                                                     ushort* __restrict__ Wt,
                                                     int K, int N) {
    __shared__ ushort tile[32][33];
    int bi = blockIdx.y;   // K / 32
    int bj = blockIdx.x;   // N / 32
    int tx = threadIdx.x;  // 32
    int ty = threadIdx.y;  // 8
#pragma unroll
    for (int r = 0; r < 4; ++r) {
        int krow = bi * 32 + ty + r * 8;
        int ncol = bj * 32 + tx;
        tile[ty + r * 8][tx] = f2bf(W[(size_t)krow * N + ncol]);
    }
    __syncthreads();
#pragma unroll
    for (int r = 0; r < 4; ++r) {
        int nrow = bj * 32 + ty + r * 8;
        int kcol = bi * 32 + tx;
        Wt[(size_t)nrow * K + kcol] = tile[tx][ty + r * 8];
    }
}

// ---------------- RMSNorm: fp32 in -> bf16 out --------------------------------
__global__ __launch_bounds__(256) void rmsnorm_k(const float* __restrict__ x,
                                                 const float* __restrict__ g,
                                                 ushort* __restrict__ out) {
    int row = blockIdx.x;
    int t = threadIdx.x;
    int w = t >> 6, l = t & 63;
    const float4 v = reinterpret_cast<const float4*>(x + (size_t)row * BDIM)[t];
    float ss = v.x * v.x + v.y * v.y + v.z * v.z + v.w * v.w;
#pragma unroll
    for (int m = 1; m <= 32; m <<= 1) ss += __shfl_xor(ss, m);
    __shared__ float wsum[4];
    if (l == 0) wsum[w] = ss;
    __syncthreads();
    float tot = wsum[0] + wsum[1] + wsum[2] + wsum[3];
    float r = rsqrtf(tot * (1.0f / BDIM) + 1e-6f);
    const float4 gv = reinterpret_cast<const float4*>(g)[t];
    ushort4 o;
    o.x = f2bf(v.x * r * gv.x);
    o.y = f2bf(v.y * r * gv.y);
    o.z = f2bf(v.z * r * gv.z);
    o.w = f2bf(v.w * r * gv.w);
    reinterpret_cast<ushort4*>(out + (size_t)row * BDIM)[t] = o;
}

// ---------------- T5 relative position bias table: btab[h][d], d = k-q+2047 ---
__global__ void bias_table_k(const float* __restrict__ rel, float* __restrict__ btab) {
    int idx = blockIdx.x * 256 + threadIdx.x;
    if (idx >= HEADS * 4095) return;
    int h = idx / 4095;
    int d = idx % 4095;
    int rp = d - 2047;                 // mem - ctx
    int bucket = rp > 0 ? 16 : 0;
    int rpa = rp < 0 ? -rp : rp;
    if (rpa < 8) {
        bucket += rpa;
    } else {
        int large = 8 + (int)(logf((float)rpa * 0.125f) * (1.0f / logf(16.0f)) * 8.0f);
        bucket += large < 15 ? large : 15;
    }
    btab[idx] = rel[bucket * HEADS + h];
}

// ---------------- bf16 GEMM, B pre-transposed (Bt is N x K) -------------------
// MODE 0: bf16 out = A@B ;  MODE 1: f32 out = res + A@B ;  MODE 2: bf16 out = relu(A@B)
template <int MODE>
__global__ __launch_bounds__(256) void gemm_bt(const ushort* __restrict__ A,
                                               const ushort* __restrict__ Bt,
                                               void* Cout, const float* res,
                                               int M, int N, int K) {
    __shared__ __align__(16) ushort As[128 * 64];
    __shared__ __align__(16) ushort Bs[128 * 64];
    const int tid = threadIdx.x;
    const int w = tid >> 6, l = tid & 63;
    const int wm = w >> 1, wn = w & 1;
    const int rowA0 = blockIdx.y * 128;
    const int colB0 = blockIdx.x * 128;
    const int lr = l >> 3;
    const int lc = (l & 7) * 8;
    const int c = l & 15, gq = l >> 4;
    f32x4_t acc[4][4] = {};

    for (int k0 = 0; k0 < K; k0 += 64) {
        __syncthreads();
#pragma unroll
        for (int i = 0; i < 4; ++i) {
            int r = i * 32 + w * 8;
            __builtin_amdgcn_global_load_lds(
                (const __attribute__((address_space(1))) uint32_t*)(A + (size_t)(rowA0 + r + lr) * K + k0 + lc),
                (__attribute__((address_space(3))) uint32_t*)(&As[r * 64]), 16, 0, 0);
            __builtin_amdgcn_global_load_lds(
                (const __attribute__((address_space(1))) uint32_t*)(Bt + (size_t)(colB0 + r + lr) * K + k0 + lc),
                (__attribute__((address_space(3))) uint32_t*)(&Bs[r * 64]), 16, 0, 0);
        }
        __syncthreads();
#pragma unroll
        for (int kk = 0; kk < 2; ++kk) {
            bf16x8_t av[4], bv[4];
#pragma unroll
            for (int mf = 0; mf < 4; ++mf)
                av[mf] = *(const bf16x8_t*)&As[(wm * 64 + mf * 16 + c) * 64 + kk * 32 + gq * 8];
#pragma unroll
            for (int nf = 0; nf < 4; ++nf)
                bv[nf] = *(const bf16x8_t*)&Bs[(wn * 64 + nf * 16 + c) * 64 + kk * 32 + gq * 8];
#pragma unroll
            for (int mf = 0; mf < 4; ++mf)
#pragma unroll
                for (int nf = 0; nf < 4; ++nf)
                    acc[mf][nf] = __builtin_amdgcn_mfma_f32_16x16x32_bf16(av[mf], bv[nf], acc[mf][nf], 0, 0, 0);
        }
    }
#pragma unroll
    for (int mf = 0; mf < 4; ++mf) {
#pragma unroll
        for (int nf = 0; nf < 4; ++nf) {
#pragma unroll
            for (int i = 0; i < 4; ++i) {
                int row = rowA0 + wm * 64 + mf * 16 + gq * 4 + i;
                int col = colB0 + wn * 64 + nf * 16 + c;
                size_t idx = (size_t)row * N + col;
                float vv = acc[mf][nf][i];
                if (MODE == 0) {
                    ((ushort*)Cout)[idx] = f2bf(vv);
                } else if (MODE == 1) {
                    ((float*)Cout)[idx] = res[idx] + vv;
                } else {
                    ((ushort*)Cout)[idx] = f2bf(vv > 0.f ? vv : 0.f);
                }
            }
        }
    }
}

// ---------------- flash attention with T5 bias, no 1/sqrt(d) scale ------------
// grid: x = q-tile (L/64), y = b*H + h. block = 256 (4 waves x 16 q-rows).
__global__ __launch_bounds__(256) void attn_fwd(const ushort* __restrict__ qb,
                                                const ushort* __restrict__ kb,
                                                const ushort* __restrict__ vb,
                                                const float* __restrict__ btab,
                                                ushort* __restrict__ ob) {
    const int tid = threadIdx.x, w = tid >> 6, l = tid & 63;
    const int bh = blockIdx.y, b = bh >> 4, h = bh & 15;
    const int qt = blockIdx.x;
    __shared__ __align__(16) ushort Vt[64 * 72];       // [hd][key^swz], stride 72
    __shared__ __align__(16) ushort Pl[4][16 * 72];    // per-wave P, stride 72
    const size_t hbase = (size_t)b * LSEQ * BDIM + h * HDIM;
    const int q0 = qt * 64 + w * 16;
    const int c = l & 15, g = l >> 4;

    bf16x8_t aq[2];
#pragma unroll
    for (int kk = 0; kk < 2; ++kk)
        aq[kk] = *(const bf16x8_t*)(qb + hbase + (size_t)(q0 + c) * BDIM + kk * 32 + g * 8);

    float mrow[4], lrow[4];
    f32x4_t o[4] = {};
#pragma unroll
    for (int i = 0; i < 4; ++i) { mrow[i] = -INFINITY; lrow[i] = 0.f; }
    const float* bt = btab + h * 4095;

    for (int kt = 0; kt < 32; ++kt) {
        const int key0 = kt * 64;
        __syncthreads();
        // stage V transposed (+ key-XOR swizzle) into LDS
#pragma unroll
        for (int it = 0; it < 2; ++it) {
            int key = it * 32 + (tid >> 3);
            int hd0 = (tid & 7) * 8;
            union { bf16x8_t v; ushort s[8]; } u;
            u.v = *(const bf16x8_t*)(vb + hbase + (size_t)(key0 + key) * BDIM + hd0);
            int sw = (tid & 7) << 3;  // == ((hd>>3)<<3) for hd in [hd0, hd0+8)
#pragma unroll
            for (int j = 0; j < 8; ++j)
                Vt[(hd0 + j) * 72 + (key ^ sw)] = u.s[j];
        }
        __syncthreads();

        // S = Q K^T (+bias)
        f32x4_t s[4];
#pragma unroll
        for (int nf = 0; nf < 4; ++nf) {
            s[nf] = (f32x4_t){0.f, 0.f, 0.f, 0.f};
#pragma unroll
            for (int kk = 0; kk < 2; ++kk) {
                bf16x8_t bk = *(const bf16x8_t*)(kb + hbase + (size_t)(key0 + nf * 16 + c) * BDIM + kk * 32 + g * 8);
                s[nf] = __builtin_amdgcn_mfma_f32_16x16x32_bf16(aq[kk], bk, s[nf], 0, 0, 0);
            }
        }
        float tmax[4];
#pragma unroll
        for (int i = 0; i < 4; ++i) {
            int qrow = q0 + g * 4 + i;
            float tm = -INFINITY;
#pragma unroll
            for (int nf = 0; nf < 4; ++nf) {
                int key = key0 + nf * 16 + c;
                s[nf][i] += bt[key - qrow + 2047];
                tm = fmaxf(tm, s[nf][i]);
            }
            tmax[i] = tm;
        }
#pragma unroll
        for (int i = 0; i < 4; ++i) {
#pragma unroll
            for (int m = 1; m <= 8; m <<= 1)
                tmax[i] = fmaxf(tmax[i], __shfl_xor(tmax[i], m));
        }
        float p[4][4];
#pragma unroll
        for (int i = 0; i < 4; ++i) {
            float mn = fmaxf(mrow[i], tmax[i]);
            float sc = __expf(mrow[i] - mn);
            mrow[i] = mn;
            float rs = 0.f;
#pragma unroll
            for (int nf = 0; nf < 4; ++nf) {
                p[nf][i] = __expf(s[nf][i] - mn);
                rs += p[nf][i];
            }
#pragma unroll
            for (int m = 1; m <= 8; m <<= 1) rs += __shfl_xor(rs, m);
            lrow[i] = lrow[i] * sc + rs;
#pragma unroll
            for (int hf = 0; hf < 4; ++hf) o[hf][i] *= sc;
        }
        // P -> per-wave LDS (A-operand layout for PV)
        ushort* Pw = Pl[w];
#pragma unroll
        for (int i = 0; i < 4; ++i)
#pragma unroll
            for (int nf = 0; nf < 4; ++nf)
                Pw[(g * 4 + i) * 72 + nf * 16 + c] = f2bf(p[nf][i]);
        // O += P @ V
#pragma unroll
        for (int kk = 0; kk < 2; ++kk) {
            bf16x8_t pa = *(const bf16x8_t*)&Pw[c * 72 + kk * 32 + g * 8];
#pragma unroll
            for (int hf = 0; hf < 4; ++hf) {
                int hd = hf * 16 + c;
                bf16x8_t bv = *(const bf16x8_t*)&Vt[hd * 72 + ((kk * 32 + g * 8) ^ ((hd >> 3) << 3))];
                o[hf] = __builtin_amdgcn_mfma_f32_16x16x32_bf16(pa, bv, o[hf], 0, 0, 0);
            }
        }
    }
#pragma unroll
    for (int i = 0; i < 4; ++i) {
        float inv = 1.f / lrow[i];
        int qrow = q0 + g * 4 + i;
#pragma unroll
        for (int hf = 0; hf < 4; ++hf)
            ob[hbase + (size_t)qrow * BDIM + hf * 16 + c] = f2bf(o[hf][i] * inv);
    }
}

extern "C" void kernel_launch(void* const* d_in, const int* in_sizes, int n_in,
                              void* d_out, int out_size, void* d_ws, size_t ws_size,
                              hipStream_t stream) {
    const float* x   = (const float*)d_in[0];
    const float* Wq  = (const float*)d_in[1];
    const float* Wk  = (const float*)d_in[2];
    const float* Wv  = (const float*)d_in[3];
    const float* Wo  = (const float*)d_in[4];
    const float* W1  = (const float*)d_in[5];
    const float* W2  = (const float*)d_in[6];
    const float* g1  = (const float*)d_in[7];
    const float* g2  = (const float*)d_in[8];
    const float* rel = (const float*)d_in[9];
    float* out = (float*)d_out;

    char* ws = (char*)d_ws;
    const size_t MB = 1024 * 1024;
    ushort* wqT  = (ushort*)(ws + 0 * MB);
    ushort* wkT  = (ushort*)(ws + 2 * MB);
    ushort* wvT  = (ushort*)(ws + 4 * MB);
    ushort* woT  = (ushort*)(ws + 6 * MB);
    ushort* w1T  = (ushort*)(ws + 8 * MB);    // 4096 x 1024
    ushort* w2T  = (ushort*)(ws + 16 * MB);   // 1024 x 4096
    float*  btab = (float*)(ws + 24 * MB);
    ushort* hbuf = (ushort*)(ws + 25 * MB);   // h, then attn_out
    ushort* qbuf = (ushort*)(ws + 33 * MB);   // q, then h2
    ushort* kbuf = (ushort*)(ws + 41 * MB);
    ushort* vbuf = (ushort*)(ws + 49 * MB);
    ushort* f1b  = (ushort*)(ws + 57 * MB);   // 4096 x 4096 bf16, ends at 89MB
    (void)in_sizes; (void)n_in; (void)out_size; (void)ws_size;

    dim3 tb(32, 8);
    transpose_cvt<<<dim3(32, 32),  tb, 0, stream>>>(Wq, wqT, 1024, 1024);
    transpose_cvt<<<dim3(32, 32),  tb, 0, stream>>>(Wk, wkT, 1024, 1024);
    transpose_cvt<<<dim3(32, 32),  tb, 0, stream>>>(Wv, wvT, 1024, 1024);
    transpose_cvt<<<dim3(32, 32),  tb, 0, stream>>>(Wo, woT, 1024, 1024);
    transpose_cvt<<<dim3(128, 32), tb, 0, stream>>>(W1, w1T, 1024, 4096);
    transpose_cvt<<<dim3(32, 128), tb, 0, stream>>>(W2, w2T, 4096, 1024);
    bias_table_k<<<256, 256, 0, stream>>>(rel, btab);

    rmsnorm_k<<<4096, 256, 0, stream>>>(x, g1, hbuf);
    gemm_bt<0><<<dim3(8, 32), 256, 0, stream>>>(hbuf, wqT, qbuf, nullptr, 4096, 1024, 1024);
    gemm_bt<0><<<dim3(8, 32), 256, 0, stream>>>(hbuf, wkT, kbuf, nullptr, 4096, 1024, 1024);
    gemm_bt<0><<<dim3(8, 32), 256, 0, stream>>>(hbuf, wvT, vbuf, nullptr, 4096, 1024, 1024);
    attn_fwd<<<dim3(32, 32), 256, 0, stream>>>(qbuf, kbuf, vbuf, btab, hbuf);
    gemm_bt<1><<<dim3(8, 32), 256, 0, stream>>>(hbuf, woT, out, x, 4096, 1024, 1024);
    rmsnorm_k<<<4096, 256, 0, stream>>>(out, g2, qbuf);
    gemm_bt<2><<<dim3(32, 32), 256, 0, stream>>>(qbuf, w1T, f1b, nullptr, 4096, 4096, 1024);
    gemm_bt<1><<<dim3(8, 32), 256, 0, stream>>>(f1b, w2T, out, out, 4096, 1024, 4096);
}

// Round 2
// 521.495 us; speedup vs baseline: 1.0558x; 1.0558x over previous
//
#include <hip/hip_runtime.h>
#include <hip/hip_bf16.h>
#include <math.h>

#define BDIM 1024
#define HEADS 16
#define HDIM 64
#define LSEQ 2048
#define NBATCH 2
#define DFFDIM 4096
#define QKVN 3072

typedef __bf16 bf16x8_t __attribute__((ext_vector_type(8)));
typedef float f32x4_t __attribute__((ext_vector_type(4)));

__device__ __forceinline__ ushort f2bf(float f) {
    union { __hip_bfloat16 b; ushort u; } cv;
    cv.b = __float2bfloat16(f);
    return cv.u;
}

// ---------------- transpose + fp32->bf16 convert: Wt[n][k] = bf16(W[k][n]) ----
__global__ __launch_bounds__(256) void transpose_cvt(const float* __restrict__ W,
                                                     ushort* __restrict__ Wt,
                                                     int K, int N) {
    __shared__ ushort tile[32][33];
    int bi = blockIdx.y;   // K / 32
    int bj = blockIdx.x;   // N / 32
    int tx = threadIdx.x;  // 32
    int ty = threadIdx.y;  // 8
#pragma unroll
    for (int r = 0; r < 4; ++r) {
        int krow = bi * 32 + ty + r * 8;
        int ncol = bj * 32 + tx;
        tile[ty + r * 8][tx] = f2bf(W[(size_t)krow * N + ncol]);
    }
    __syncthreads();
#pragma unroll
    for (int r = 0; r < 4; ++r) {
        int nrow = bj * 32 + ty + r * 8;
        int kcol = bi * 32 + tx;
        Wt[(size_t)nrow * K + kcol] = tile[tx][ty + r * 8];
    }
}

// ---------------- per-head V transpose: vT[(b,h)][hd][key] = V[b][key][h][hd] --
// V lives in fused qkv buffer at column offset 2048, row stride 3072.
__global__ __launch_bounds__(256) void vtrans(const ushort* __restrict__ qkv,
                                              ushort* __restrict__ vT) {
    __shared__ ushort t[64][72];
    const int ktile = blockIdx.x;           // key / 64
    const int bh = blockIdx.y;
    const int b = bh >> 4, h = bh & 15;
    const int tid = threadIdx.x;
    const int r = tid >> 2;                 // 0..63
    const int c0 = (tid & 3) * 16;          // 0,16,32,48
    const ushort* src = qkv + (size_t)(b * LSEQ + ktile * 64 + r) * QKVN + 2048 + h * HDIM + c0;
    union { bf16x8_t v; ushort s[8]; } u0, u1;
    u0.v = *(const bf16x8_t*)src;
    u1.v = *(const bf16x8_t*)(src + 8);
#pragma unroll
    for (int j = 0; j < 8; ++j) { t[r][c0 + j] = u0.s[j]; t[r][c0 + 8 + j] = u1.s[j]; }
    __syncthreads();
    const int hd = tid >> 2;
    union { bf16x8_t v; ushort s[8]; } w0, w1;
#pragma unroll
    for (int j = 0; j < 8; ++j) { w0.s[j] = t[c0 + j][hd]; w1.s[j] = t[c0 + 8 + j][hd]; }
    ushort* dst = vT + (size_t)(bh * HDIM + hd) * LSEQ + ktile * 64 + c0;
    *(bf16x8_t*)dst = w0.v;
    *(bf16x8_t*)(dst + 8) = w1.v;
}

// ---------------- RMSNorm: fp32 in -> bf16 out --------------------------------
__global__ __launch_bounds__(256) void rmsnorm_k(const float* __restrict__ x,
                                                 const float* __restrict__ g,
                                                 ushort* __restrict__ out) {
    int row = blockIdx.x;
    int t = threadIdx.x;
    int w = t >> 6, l = t & 63;
    const float4 v = reinterpret_cast<const float4*>(x + (size_t)row * BDIM)[t];
    float ss = v.x * v.x + v.y * v.y + v.z * v.z + v.w * v.w;
#pragma unroll
    for (int m = 1; m <= 32; m <<= 1) ss += __shfl_xor(ss, m);
    __shared__ float wsum[4];
    if (l == 0) wsum[w] = ss;
    __syncthreads();
    float tot = wsum[0] + wsum[1] + wsum[2] + wsum[3];
    float r = rsqrtf(tot * (1.0f / BDIM) + 1e-6f);
    const float4 gv = reinterpret_cast<const float4*>(g)[t];
    ushort4 o;
    o.x = f2bf(v.x * r * gv.x);
    o.y = f2bf(v.y * r * gv.y);
    o.z = f2bf(v.z * r * gv.z);
    o.w = f2bf(v.w * r * gv.w);
    reinterpret_cast<ushort4*>(out + (size_t)row * BDIM)[t] = o;
}

// ---------------- T5 relative position bias table: btab[h][d], d = k-q+2047 ---
__global__ void bias_table_k(const float* __restrict__ rel, float* __restrict__ btab) {
    int idx = blockIdx.x * 256 + threadIdx.x;
    if (idx >= HEADS * 4095) return;
    int h = idx / 4095;
    int d = idx % 4095;
    int rp = d - 2047;                 // mem - ctx
    int bucket = rp > 0 ? 16 : 0;
    int rpa = rp < 0 ? -rp : rp;
    if (rpa < 8) {
        bucket += rpa;
    } else {
        int large = 8 + (int)(logf((float)rpa * 0.125f) * (1.0f / logf(16.0f)) * 8.0f);
        bucket += large < 15 ? large : 15;
    }
    btab[idx] = rel[bucket * HEADS + h];
}

// ---------------- bf16 GEMM, B pre-transposed (Bt is N x K), 1D grid + XCD swz
// MODE 0: bf16 out = A@B ;  MODE 1: f32 out = res + A@B ;  MODE 2: bf16 out = relu(A@B)
template <int MODE>
__global__ __launch_bounds__(256) void gemm_bt(const ushort* __restrict__ A,
                                               const ushort* __restrict__ Bt,
                                               void* Cout, const float* res,
                                               int M, int N, int K, int nbx) {
    __shared__ __align__(16) ushort As[128 * 64];
    __shared__ __align__(16) ushort Bs[128 * 64];
    const int nwg = gridDim.x;
    const int bid = blockIdx.x;
    const int swz = (bid & 7) * (nwg >> 3) + (bid >> 3);   // nwg % 8 == 0 always
    const int bx = swz % nbx, by = swz / nbx;
    const int tid = threadIdx.x;
    const int w = tid >> 6, l = tid & 63;
    const int wm = w >> 1, wn = w & 1;
    const int rowA0 = by * 128;
    const int colB0 = bx * 128;
    const int lr = l >> 3;
    const int lc = (l & 7) * 8;
    const int c = l & 15, gq = l >> 4;
    f32x4_t acc[4][4] = {};

    for (int k0 = 0; k0 < K; k0 += 64) {
        __syncthreads();
#pragma unroll
        for (int i = 0; i < 4; ++i) {
            int r = i * 32 + w * 8;
            __builtin_amdgcn_global_load_lds(
                (const __attribute__((address_space(1))) uint32_t*)(A + (size_t)(rowA0 + r + lr) * K + k0 + lc),
                (__attribute__((address_space(3))) uint32_t*)(&As[r * 64]), 16, 0, 0);
            __builtin_amdgcn_global_load_lds(
                (const __attribute__((address_space(1))) uint32_t*)(Bt + (size_t)(colB0 + r + lr) * K + k0 + lc),
                (__attribute__((address_space(3))) uint32_t*)(&Bs[r * 64]), 16, 0, 0);
        }
        __syncthreads();
#pragma unroll
        for (int kk = 0; kk < 2; ++kk) {
            bf16x8_t av[4], bv[4];
#pragma unroll
            for (int mf = 0; mf < 4; ++mf)
                av[mf] = *(const bf16x8_t*)&As[(wm * 64 + mf * 16 + c) * 64 + kk * 32 + gq * 8];
#pragma unroll
            for (int nf = 0; nf < 4; ++nf)
                bv[nf] = *(const bf16x8_t*)&Bs[(wn * 64 + nf * 16 + c) * 64 + kk * 32 + gq * 8];
#pragma unroll
            for (int mf = 0; mf < 4; ++mf)
#pragma unroll
                for (int nf = 0; nf < 4; ++nf)
                    acc[mf][nf] = __builtin_amdgcn_mfma_f32_16x16x32_bf16(av[mf], bv[nf], acc[mf][nf], 0, 0, 0);
        }
    }
#pragma unroll
    for (int mf = 0; mf < 4; ++mf) {
#pragma unroll
        for (int nf = 0; nf < 4; ++nf) {
#pragma unroll
            for (int i = 0; i < 4; ++i) {
                int row = rowA0 + wm * 64 + mf * 16 + gq * 4 + i;
                int col = colB0 + wn * 64 + nf * 16 + c;
                size_t idx = (size_t)row * N + col;
                float vv = acc[mf][nf][i];
                if (MODE == 0) {
                    ((ushort*)Cout)[idx] = f2bf(vv);
                } else if (MODE == 1) {
                    ((float*)Cout)[idx] = res[idx] + vv;
                } else {
                    ((ushort*)Cout)[idx] = f2bf(vv > 0.f ? vv : 0.f);
                }
            }
        }
    }
}

// ---------------- flash attention, barrier-free: K from global, V^T from global
// grid: x = q-tile (L/64), y = b*H + h. block = 256 (4 independent waves x 16 q).
__global__ __launch_bounds__(256) void attn_fwd(const ushort* __restrict__ qkv,
                                                const ushort* __restrict__ vT,
                                                const float* __restrict__ btab,
                                                ushort* __restrict__ ob) {
    const int tid = threadIdx.x, w = tid >> 6, l = tid & 63;
    const int bh = blockIdx.y, b = bh >> 4, h = bh & 15;
    const int qt = blockIdx.x;
    __shared__ __align__(16) ushort Pl[4][16 * 72];    // per-wave P, stride 72
    const int q0 = qt * 64 + w * 16;
    const int c = l & 15, g = l >> 4;
    const size_t rowbase = (size_t)b * LSEQ * QKVN;
    const ushort* qp = qkv + rowbase + h * HDIM;
    const ushort* kp = qkv + rowbase + BDIM + h * HDIM;
    const ushort* vtp = vT + (size_t)bh * HDIM * LSEQ;

    bf16x8_t aq[2];
#pragma unroll
    for (int kk = 0; kk < 2; ++kk)
        aq[kk] = *(const bf16x8_t*)(qp + (size_t)(q0 + c) * QKVN + kk * 32 + g * 8);

    float mrow[4], lrow[4];
    f32x4_t o[4] = {};
#pragma unroll
    for (int i = 0; i < 4; ++i) { mrow[i] = -INFINITY; lrow[i] = 0.f; }
    const float* bt = btab + h * 4095;

    for (int kt = 0; kt < 32; ++kt) {
        const int key0 = kt * 64;
        // S = Q K^T  (K B-fragments straight from global; L2-resident)
        f32x4_t s[4];
#pragma unroll
        for (int nf = 0; nf < 4; ++nf) {
            s[nf] = (f32x4_t){0.f, 0.f, 0.f, 0.f};
#pragma unroll
            for (int kk = 0; kk < 2; ++kk) {
                bf16x8_t bk = *(const bf16x8_t*)(kp + (size_t)(key0 + nf * 16 + c) * QKVN + kk * 32 + g * 8);
                s[nf] = __builtin_amdgcn_mfma_f32_16x16x32_bf16(aq[kk], bk, s[nf], 0, 0, 0);
            }
        }
        float tmax[4];
#pragma unroll
        for (int i = 0; i < 4; ++i) {
            int qrow = q0 + g * 4 + i;
            float tm = -INFINITY;
#pragma unroll
            for (int nf = 0; nf < 4; ++nf) {
                int key = key0 + nf * 16 + c;
                s[nf][i] += bt[key - qrow + 2047];
                tm = fmaxf(tm, s[nf][i]);
            }
            tmax[i] = tm;
        }
#pragma unroll
        for (int i = 0; i < 4; ++i) {
#pragma unroll
            for (int m = 1; m <= 8; m <<= 1)
                tmax[i] = fmaxf(tmax[i], __shfl_xor(tmax[i], m));
        }
        float p[4][4];
#pragma unroll
        for (int i = 0; i < 4; ++i) {
            float mn = fmaxf(mrow[i], tmax[i]);
            float sc = __expf(mrow[i] - mn);
            mrow[i] = mn;
            float rs = 0.f;
#pragma unroll
            for (int nf = 0; nf < 4; ++nf) {
                p[nf][i] = __expf(s[nf][i] - mn);
                rs += p[nf][i];
            }
#pragma unroll
            for (int m = 1; m <= 8; m <<= 1) rs += __shfl_xor(rs, m);
            lrow[i] = lrow[i] * sc + rs;
#pragma unroll
            for (int hf = 0; hf < 4; ++hf) o[hf][i] *= sc;
        }
        // P -> per-wave LDS (A-operand relayout), no barrier: wave-local
        ushort* Pw = Pl[w];
#pragma unroll
        for (int i = 0; i < 4; ++i)
#pragma unroll
            for (int nf = 0; nf < 4; ++nf)
                Pw[(g * 4 + i) * 72 + nf * 16 + c] = f2bf(p[nf][i]);
        // O += P @ V   (V^T B-fragments straight from global; contiguous)
#pragma unroll
        for (int kk = 0; kk < 2; ++kk) {
            bf16x8_t pa = *(const bf16x8_t*)&Pw[c * 72 + kk * 32 + g * 8];
#pragma unroll
            for (int hf = 0; hf < 4; ++hf) {
                bf16x8_t bv = *(const bf16x8_t*)(vtp + (size_t)(hf * 16 + c) * LSEQ + key0 + kk * 32 + g * 8);
                o[hf] = __builtin_amdgcn_mfma_f32_16x16x32_bf16(pa, bv, o[hf], 0, 0, 0);
            }
        }
    }
#pragma unroll
    for (int i = 0; i < 4; ++i) {
        float inv = 1.f / lrow[i];
        int qrow = q0 + g * 4 + i;
#pragma unroll
        for (int hf = 0; hf < 4; ++hf)
            ob[(size_t)(b * LSEQ + qrow) * BDIM + h * HDIM + hf * 16 + c] = f2bf(o[hf][i] * inv);
    }
}

extern "C" void kernel_launch(void* const* d_in, const int* in_sizes, int n_in,
                              void* d_out, int out_size, void* d_ws, size_t ws_size,
                              hipStream_t stream) {
    const float* x   = (const float*)d_in[0];
    const float* Wq  = (const float*)d_in[1];
    const float* Wk  = (const float*)d_in[2];
    const float* Wv  = (const float*)d_in[3];
    const float* Wo  = (const float*)d_in[4];
    const float* W1  = (const float*)d_in[5];
    const float* W2  = (const float*)d_in[6];
    const float* g1  = (const float*)d_in[7];
    const float* g2  = (const float*)d_in[8];
    const float* rel = (const float*)d_in[9];
    float* out = (float*)d_out;

    char* ws = (char*)d_ws;
    const size_t MB = 1024 * 1024;
    ushort* wqkvT = (ushort*)(ws + 0 * MB);    // 3072 x 1024 bf16 = 6MB
    ushort* woT   = (ushort*)(ws + 6 * MB);    // 2MB
    ushort* w1T   = (ushort*)(ws + 8 * MB);    // 4096 x 1024 = 8MB
    ushort* w2T   = (ushort*)(ws + 16 * MB);   // 1024 x 4096 = 8MB
    float*  btab  = (float*)(ws + 24 * MB);    // 256KB
    ushort* hbuf  = (ushort*)(ws + 25 * MB);   // 8MB: h, then attn_out, then h2
    ushort* qkvb  = (ushort*)(ws + 33 * MB);   // 4096 x 3072 = 24MB
    ushort* f1b   = (ushort*)(ws + 33 * MB);   // 32MB, reuses qkv+vT after attn
    ushort* vTb   = (ushort*)(ws + 57 * MB);   // 8MB; total 65MB
    (void)in_sizes; (void)n_in; (void)out_size; (void)ws_size;

    dim3 tb(32, 8);
    transpose_cvt<<<dim3(32, 32),  tb, 0, stream>>>(Wq, wqkvT,                1024, 1024);
    transpose_cvt<<<dim3(32, 32),  tb, 0, stream>>>(Wk, wqkvT + 1024 * 1024,  1024, 1024);
    transpose_cvt<<<dim3(32, 32),  tb, 0, stream>>>(Wv, wqkvT + 2048 * 1024,  1024, 1024);
    transpose_cvt<<<dim3(32, 32),  tb, 0, stream>>>(Wo, woT, 1024, 1024);
    transpose_cvt<<<dim3(128, 32), tb, 0, stream>>>(W1, w1T, 1024, 4096);
    transpose_cvt<<<dim3(32, 128), tb, 0, stream>>>(W2, w2T, 4096, 1024);
    bias_table_k<<<256, 256, 0, stream>>>(rel, btab);

    rmsnorm_k<<<4096, 256, 0, stream>>>(x, g1, hbuf);
    gemm_bt<0><<<768, 256, 0, stream>>>(hbuf, wqkvT, qkvb, nullptr, 4096, QKVN, 1024, 24);
    vtrans<<<dim3(32, 32), 256, 0, stream>>>(qkvb, vTb);
    attn_fwd<<<dim3(32, 32), 256, 0, stream>>>(qkvb, vTb, btab, hbuf);
    gemm_bt<1><<<256, 256, 0, stream>>>(hbuf, woT, out, x, 4096, 1024, 1024, 8);
    rmsnorm_k<<<4096, 256, 0, stream>>>(out, g2, hbuf);
    gemm_bt<2><<<1024, 256, 0, stream>>>(hbuf, w1T, f1b, nullptr, 4096, DFFDIM, 1024, 32);
    gemm_bt<1><<<256, 256, 0, stream>>>(f1b, w2T, out, out, 4096, 1024, DFFDIM, 8);
}

// Round 3
// 497.243 us; speedup vs baseline: 1.1073x; 1.0488x over previous
//
#include <hip/hip_runtime.h>
#include <hip/hip_bf16.h>
#include <math.h>

#define BDIM 1024
#define HEADS 16
#define HDIM 64
#define LSEQ 2048
#define NBATCH 2
#define DFFDIM 4096
#define QKVN 3072

typedef __bf16 bf16x8_t __attribute__((ext_vector_type(8)));
typedef float f32x4_t __attribute__((ext_vector_type(4)));

__device__ __forceinline__ ushort f2bf(float f) {
    union { __hip_bfloat16 b; ushort u; } cv;
    cv.b = __float2bfloat16(f);
    return cv.u;
}

// ---------------- transpose + fp32->bf16 convert: Wt[n][k] = bf16(W[k][n]) ----
__global__ __launch_bounds__(256) void transpose_cvt(const float* __restrict__ W,
                                                     ushort* __restrict__ Wt,
                                                     int K, int N) {
    __shared__ ushort tile[32][33];
    int bi = blockIdx.y;   // K / 32
    int bj = blockIdx.x;   // N / 32
    int tx = threadIdx.x;  // 32
    int ty = threadIdx.y;  // 8
#pragma unroll
    for (int r = 0; r < 4; ++r) {
        int krow = bi * 32 + ty + r * 8;
        int ncol = bj * 32 + tx;
        tile[ty + r * 8][tx] = f2bf(W[(size_t)krow * N + ncol]);
    }
    __syncthreads();
#pragma unroll
    for (int r = 0; r < 4; ++r) {
        int nrow = bj * 32 + ty + r * 8;
        int kcol = bi * 32 + tx;
        Wt[(size_t)nrow * K + kcol] = tile[tx][ty + r * 8];
    }
}

// ---------------- per-head V transpose: vT[(b,h)][hd][key] = V[b][key][h][hd] --
__global__ __launch_bounds__(256) void vtrans(const ushort* __restrict__ qkv,
                                              ushort* __restrict__ vT) {
    __shared__ ushort t[64][72];
    const int ktile = blockIdx.x;           // key / 64
    const int bh = blockIdx.y;
    const int b = bh >> 4, h = bh & 15;
    const int tid = threadIdx.x;
    const int r = tid >> 2;                 // 0..63
    const int c0 = (tid & 3) * 16;          // 0,16,32,48
    const ushort* src = qkv + (size_t)(b * LSEQ + ktile * 64 + r) * QKVN + 2048 + h * HDIM + c0;
    union { bf16x8_t v; ushort s[8]; } u0, u1;
    u0.v = *(const bf16x8_t*)src;
    u1.v = *(const bf16x8_t*)(src + 8);
#pragma unroll
    for (int j = 0; j < 8; ++j) { t[r][c0 + j] = u0.s[j]; t[r][c0 + 8 + j] = u1.s[j]; }
    __syncthreads();
    const int hd = tid >> 2;
    union { bf16x8_t v; ushort s[8]; } w0, w1;
#pragma unroll
    for (int j = 0; j < 8; ++j) { w0.s[j] = t[c0 + j][hd]; w1.s[j] = t[c0 + 8 + j][hd]; }
    ushort* dst = vT + (size_t)(bh * HDIM + hd) * LSEQ + ktile * 64 + c0;
    *(bf16x8_t*)dst = w0.v;
    *(bf16x8_t*)(dst + 8) = w1.v;
}

// ---------------- RMSNorm: fp32 in -> bf16 out --------------------------------
__global__ __launch_bounds__(256) void rmsnorm_k(const float* __restrict__ x,
                                                 const float* __restrict__ g,
                                                 ushort* __restrict__ out) {
    int row = blockIdx.x;
    int t = threadIdx.x;
    int w = t >> 6, l = t & 63;
    const float4 v = reinterpret_cast<const float4*>(x + (size_t)row * BDIM)[t];
    float ss = v.x * v.x + v.y * v.y + v.z * v.z + v.w * v.w;
#pragma unroll
    for (int m = 1; m <= 32; m <<= 1) ss += __shfl_xor(ss, m);
    __shared__ float wsum[4];
    if (l == 0) wsum[w] = ss;
    __syncthreads();
    float tot = wsum[0] + wsum[1] + wsum[2] + wsum[3];
    float r = rsqrtf(tot * (1.0f / BDIM) + 1e-6f);
    const float4 gv = reinterpret_cast<const float4*>(g)[t];
    ushort4 o;
    o.x = f2bf(v.x * r * gv.x);
    o.y = f2bf(v.y * r * gv.y);
    o.z = f2bf(v.z * r * gv.z);
    o.w = f2bf(v.w * r * gv.w);
    reinterpret_cast<ushort4*>(out + (size_t)row * BDIM)[t] = o;
}

// ---------------- T5 relative position bias table: btab[h][d], d = k-q+2047 ---
__global__ void bias_table_k(const float* __restrict__ rel, float* __restrict__ btab) {
    int idx = blockIdx.x * 256 + threadIdx.x;
    if (idx >= HEADS * 4095) return;
    int h = idx / 4095;
    int d = idx % 4095;
    int rp = d - 2047;                 // mem - ctx
    int bucket = rp > 0 ? 16 : 0;
    int rpa = rp < 0 ? -rp : rp;
    if (rpa < 8) {
        bucket += rpa;
    } else {
        int large = 8 + (int)(logf((float)rpa * 0.125f) * (1.0f / logf(16.0f)) * 8.0f);
        bucket += large < 15 ? large : 15;
    }
    btab[idx] = rel[bucket * HEADS + h];
}

// ---------------- bf16 GEMM, B pre-transposed (Bt is N x K), 1D grid + XCD swz
// MODE 0: bf16 out = A@B ;  MODE 1: f32 out = res + A@B ;  MODE 2: bf16 out = relu(A@B)
template <int MODE, int TM, int TN>
__global__ __launch_bounds__(256) void gemm_bt(const ushort* __restrict__ A,
                                               const ushort* __restrict__ Bt,
                                               void* Cout, const float* res,
                                               int M, int N, int K, int nbx) {
    __shared__ __align__(16) ushort As[TM * 64];
    __shared__ __align__(16) ushort Bs[TN * 64];
    constexpr int MF = TM / 32, NF = TN / 32;
    const int nwg = gridDim.x;
    const int bid = blockIdx.x;
    const int swz = (bid & 7) * (nwg >> 3) + (bid >> 3);   // nwg % 8 == 0 always
    const int bx = swz % nbx, by = swz / nbx;
    const int tid = threadIdx.x;
    const int w = tid >> 6, l = tid & 63;
    const int wm = w >> 1, wn = w & 1;
    const int rowA0 = by * TM;
    const int colB0 = bx * TN;
    const int lr = l >> 3;
    const int lc = (l & 7) * 8;
    const int c = l & 15, gq = l >> 4;
    f32x4_t acc[MF][NF] = {};

    for (int k0 = 0; k0 < K; k0 += 64) {
        __syncthreads();
#pragma unroll
        for (int i = 0; i < TM / 32; ++i) {
            int r = i * 32 + w * 8;
            __builtin_amdgcn_global_load_lds(
                (const __attribute__((address_space(1))) uint32_t*)(A + (size_t)(rowA0 + r + lr) * K + k0 + lc),
                (__attribute__((address_space(3))) uint32_t*)(&As[r * 64]), 16, 0, 0);
        }
#pragma unroll
        for (int i = 0; i < TN / 32; ++i) {
            int r = i * 32 + w * 8;
            __builtin_amdgcn_global_load_lds(
                (const __attribute__((address_space(1))) uint32_t*)(Bt + (size_t)(colB0 + r + lr) * K + k0 + lc),
                (__attribute__((address_space(3))) uint32_t*)(&Bs[r * 64]), 16, 0, 0);
        }
        __syncthreads();
#pragma unroll
        for (int kk = 0; kk < 2; ++kk) {
            bf16x8_t av[MF], bv[NF];
#pragma unroll
            for (int mf = 0; mf < MF; ++mf)
                av[mf] = *(const bf16x8_t*)&As[(wm * (TM / 2) + mf * 16 + c) * 64 + kk * 32 + gq * 8];
#pragma unroll
            for (int nf = 0; nf < NF; ++nf)
                bv[nf] = *(const bf16x8_t*)&Bs[(wn * (TN / 2) + nf * 16 + c) * 64 + kk * 32 + gq * 8];
#pragma unroll
            for (int mf = 0; mf < MF; ++mf)
#pragma unroll
                for (int nf = 0; nf < NF; ++nf)
                    acc[mf][nf] = __builtin_amdgcn_mfma_f32_16x16x32_bf16(av[mf], bv[nf], acc[mf][nf], 0, 0, 0);
        }
    }
#pragma unroll
    for (int mf = 0; mf < MF; ++mf) {
#pragma unroll
        for (int nf = 0; nf < NF; ++nf) {
#pragma unroll
            for (int i = 0; i < 4; ++i) {
                int row = rowA0 + wm * (TM / 2) + mf * 16 + gq * 4 + i;
                int col = colB0 + wn * (TN / 2) + nf * 16 + c;
                size_t idx = (size_t)row * N + col;
                float vv = acc[mf][nf][i];
                if (MODE == 0) {
                    ((ushort*)Cout)[idx] = f2bf(vv);
                } else if (MODE == 1) {
                    ((float*)Cout)[idx] = res[idx] + vv;
                } else {
                    ((ushort*)Cout)[idx] = f2bf(vv > 0.f ? vv : 0.f);
                }
            }
        }
    }
}

// ---------------- flash attention, register-pipelined, barrier-free -----------
// grid: x = q-tile (L/64), y = b*H + h. block = 256 (4 independent waves x 16 q).
// Per iteration: K(kt+1), V(kt+1) prefetched into regs; bias(kt+1) prefetched
// directly into the MFMA C accumulator; defer-max skips rescale when possible.
__global__ __launch_bounds__(256, 2) void attn_fwd(const ushort* __restrict__ qkv,
                                                   const ushort* __restrict__ vT,
                                                   const float* __restrict__ btab,
                                                   ushort* __restrict__ ob) {
    const int tid = threadIdx.x, w = tid >> 6, l = tid & 63;
    const int bh = blockIdx.y, b = bh >> 4, h = bh & 15;
    const int qt = blockIdx.x;
    __shared__ __align__(16) ushort Pl[4][16 * 72];    // per-wave P, stride 72
    const int q0 = qt * 64 + w * 16;
    const int c = l & 15, g = l >> 4;
    const size_t rowbase = (size_t)b * LSEQ * QKVN;
    const ushort* qp = qkv + rowbase + h * HDIM;
    const ushort* kp = qkv + rowbase + BDIM + h * HDIM;
    const ushort* vtp = vT + (size_t)bh * HDIM * LSEQ;
    const float* bt = btab + h * 4095 + 2047 - q0 - g * 4;   // index by [key - i]

    bf16x8_t aq[2];
#pragma unroll
    for (int kk = 0; kk < 2; ++kk)
        aq[kk] = *(const bf16x8_t*)(qp + (size_t)(q0 + c) * QKVN + kk * 32 + g * 8);

    float mrow[4], lrow[4];
    f32x4_t o[4] = {};
#pragma unroll
    for (int i = 0; i < 4; ++i) { mrow[i] = -INFINITY; lrow[i] = 0.f; }

    bf16x8_t kreg[4][2], vreg[4][2];
    f32x4_t s[4];

    auto loadK = [&](int key0) {
#pragma unroll
        for (int nf = 0; nf < 4; ++nf)
#pragma unroll
            for (int kk = 0; kk < 2; ++kk)
                kreg[nf][kk] = *(const bf16x8_t*)(kp + (size_t)(key0 + nf * 16 + c) * QKVN + kk * 32 + g * 8);
    };
    auto loadV = [&](int key0) {
#pragma unroll
        for (int hf = 0; hf < 4; ++hf)
#pragma unroll
            for (int kk = 0; kk < 2; ++kk)
                vreg[hf][kk] = *(const bf16x8_t*)(vtp + (size_t)(hf * 16 + c) * LSEQ + key0 + kk * 32 + g * 8);
    };
    auto loadBias = [&](int key0) {
#pragma unroll
        for (int nf = 0; nf < 4; ++nf) {
            int key = key0 + nf * 16 + c;
#pragma unroll
            for (int i = 0; i < 4; ++i)
                s[nf][i] = bt[key - i];
        }
    };

    loadK(0);
    loadV(0);
    loadBias(0);

    for (int kt = 0; kt < 32; ++kt) {
        const int key0 = kt * 64;
        // 1. S = bias + Q K^T   (C-in pre-filled with bias)
#pragma unroll
        for (int kk = 0; kk < 2; ++kk)
#pragma unroll
            for (int nf = 0; nf < 4; ++nf)
                s[nf] = __builtin_amdgcn_mfma_f32_16x16x32_bf16(aq[kk], kreg[nf][kk], s[nf], 0, 0, 0);
        // 2. prefetch K(kt+1) — hidden under softmax + PV
        if (kt < 31) loadK(key0 + 64);
        // 3. softmax with defer-max
        float tmax[4];
#pragma unroll
        for (int i = 0; i < 4; ++i)
            tmax[i] = fmaxf(fmaxf(s[0][i], s[1][i]), fmaxf(s[2][i], s[3][i]));
#pragma unroll
        for (int i = 0; i < 4; ++i)
#pragma unroll
            for (int m = 1; m <= 8; m <<= 1)
                tmax[i] = fmaxf(tmax[i], __shfl_xor(tmax[i], m));
        int ok = (tmax[0] - mrow[0] <= 8.f) && (tmax[1] - mrow[1] <= 8.f) &&
                 (tmax[2] - mrow[2] <= 8.f) && (tmax[3] - mrow[3] <= 8.f);
        if (!__all(ok)) {
#pragma unroll
            for (int i = 0; i < 4; ++i) {
                float mn = fmaxf(mrow[i], tmax[i]);
                float sc = __expf(mrow[i] - mn);
                mrow[i] = mn;
                lrow[i] *= sc;
#pragma unroll
                for (int hf = 0; hf < 4; ++hf) o[hf][i] *= sc;
            }
        }
        float p[4][4];
#pragma unroll
        for (int i = 0; i < 4; ++i) {
            float rs = 0.f;
#pragma unroll
            for (int nf = 0; nf < 4; ++nf) {
                p[nf][i] = __expf(s[nf][i] - mrow[i]);
                rs += p[nf][i];
            }
#pragma unroll
            for (int m = 1; m <= 8; m <<= 1) rs += __shfl_xor(rs, m);
            lrow[i] += rs;
        }
        // 4. prefetch bias(kt+1) into the accumulator — L1-resident table
        if (kt < 31) loadBias(key0 + 64);
        // 5. P -> per-wave LDS (A-operand relayout), wave-local, no barrier
        ushort* Pw = Pl[w];
#pragma unroll
        for (int i = 0; i < 4; ++i)
#pragma unroll
            for (int nf = 0; nf < 4; ++nf)
                Pw[(g * 4 + i) * 72 + nf * 16 + c] = f2bf(p[nf][i]);
        bf16x8_t pa[2];
#pragma unroll
        for (int kk = 0; kk < 2; ++kk)
            pa[kk] = *(const bf16x8_t*)&Pw[c * 72 + kk * 32 + g * 8];
        // 6. O += P @ V  (V regs prefetched last iteration)
#pragma unroll
        for (int kk = 0; kk < 2; ++kk)
#pragma unroll
            for (int hf = 0; hf < 4; ++hf)
                o[hf] = __builtin_amdgcn_mfma_f32_16x16x32_bf16(pa[kk], vreg[hf][kk], o[hf], 0, 0, 0);
        // 7. prefetch V(kt+1) — hidden under next iteration's steps 1-5
        if (kt < 31) loadV(key0 + 64);
    }
#pragma unroll
    for (int i = 0; i < 4; ++i) {
        float inv = 1.f / lrow[i];
        int qrow = q0 + g * 4 + i;
#pragma unroll
        for (int hf = 0; hf < 4; ++hf)
            ob[(size_t)(b * LSEQ + qrow) * BDIM + h * HDIM + hf * 16 + c] = f2bf(o[hf][i] * inv);
    }
}

extern "C" void kernel_launch(void* const* d_in, const int* in_sizes, int n_in,
                              void* d_out, int out_size, void* d_ws, size_t ws_size,
                              hipStream_t stream) {
    const float* x   = (const float*)d_in[0];
    const float* Wq  = (const float*)d_in[1];
    const float* Wk  = (const float*)d_in[2];
    const float* Wv  = (const float*)d_in[3];
    const float* Wo  = (const float*)d_in[4];
    const float* W1  = (const float*)d_in[5];
    const float* W2  = (const float*)d_in[6];
    const float* g1  = (const float*)d_in[7];
    const float* g2  = (const float*)d_in[8];
    const float* rel = (const float*)d_in[9];
    float* out = (float*)d_out;

    char* ws = (char*)d_ws;
    const size_t MB = 1024 * 1024;
    ushort* wqkvT = (ushort*)(ws + 0 * MB);    // 3072 x 1024 bf16 = 6MB
    ushort* woT   = (ushort*)(ws + 6 * MB);    // 2MB
    ushort* w1T   = (ushort*)(ws + 8 * MB);    // 4096 x 1024 = 8MB
    ushort* w2T   = (ushort*)(ws + 16 * MB);   // 1024 x 4096 = 8MB
    float*  btab  = (float*)(ws + 24 * MB);    // 256KB
    ushort* hbuf  = (ushort*)(ws + 25 * MB);   // 8MB: h, then attn_out, then h2
    ushort* qkvb  = (ushort*)(ws + 33 * MB);   // 4096 x 3072 = 24MB
    ushort* f1b   = (ushort*)(ws + 33 * MB);   // 32MB, reuses qkv+vT after attn
    ushort* vTb   = (ushort*)(ws + 57 * MB);   // 8MB; total 65MB
    (void)in_sizes; (void)n_in; (void)out_size; (void)ws_size;

    dim3 tb(32, 8);
    transpose_cvt<<<dim3(32, 32),  tb, 0, stream>>>(Wq, wqkvT,                1024, 1024);
    transpose_cvt<<<dim3(32, 32),  tb, 0, stream>>>(Wk, wqkvT + 1024 * 1024,  1024, 1024);
    transpose_cvt<<<dim3(32, 32),  tb, 0, stream>>>(Wv, wqkvT + 2048 * 1024,  1024, 1024);
    transpose_cvt<<<dim3(32, 32),  tb, 0, stream>>>(Wo, woT, 1024, 1024);
    transpose_cvt<<<dim3(128, 32), tb, 0, stream>>>(W1, w1T, 1024, 4096);
    transpose_cvt<<<dim3(32, 128), tb, 0, stream>>>(W2, w2T, 4096, 1024);
    bias_table_k<<<256, 256, 0, stream>>>(rel, btab);

    rmsnorm_k<<<4096, 256, 0, stream>>>(x, g1, hbuf);
    gemm_bt<0, 128, 128><<<768, 256, 0, stream>>>(hbuf, wqkvT, qkvb, nullptr, 4096, QKVN, 1024, 24);
    vtrans<<<dim3(32, 32), 256, 0, stream>>>(qkvb, vTb);
    attn_fwd<<<dim3(32, 32), 256, 0, stream>>>(qkvb, vTb, btab, hbuf);
    gemm_bt<1, 128, 64><<<512, 256, 0, stream>>>(hbuf, woT, out, x, 4096, 1024, 1024, 16);
    rmsnorm_k<<<4096, 256, 0, stream>>>(out, g2, hbuf);
    gemm_bt<2, 128, 128><<<1024, 256, 0, stream>>>(hbuf, w1T, f1b, nullptr, 4096, DFFDIM, 1024, 32);
    gemm_bt<1, 128, 64><<<512, 256, 0, stream>>>(f1b, w2T, out, out, 4096, 1024, DFFDIM, 16);
}

// Round 4
// 495.456 us; speedup vs baseline: 1.1113x; 1.0036x over previous
//
#include <hip/hip_runtime.h>
#include <hip/hip_bf16.h>
#include <math.h>

#define BDIM 1024
#define HEADS 16
#define HDIM 64
#define LSEQ 2048
#define NBATCH 2
#define DFFDIM 4096
#define QKVN 3072

typedef __bf16 bf16x8_t __attribute__((ext_vector_type(8)));
typedef float f32x4_t __attribute__((ext_vector_type(4)));

__device__ __forceinline__ ushort f2bf(float f) {
    union { __hip_bfloat16 b; ushort u; } cv;
    cv.b = __float2bfloat16(f);
    return cv.u;
}

// ---------------- transpose + fp32->bf16 convert: Wt[n][k] = bf16(W[k][n]) ----
__global__ __launch_bounds__(256) void transpose_cvt(const float* __restrict__ W,
                                                     ushort* __restrict__ Wt,
                                                     int K, int N) {
    __shared__ ushort tile[32][33];
    int bi = blockIdx.y;   // K / 32
    int bj = blockIdx.x;   // N / 32
    int tx = threadIdx.x;  // 32
    int ty = threadIdx.y;  // 8
#pragma unroll
    for (int r = 0; r < 4; ++r) {
        int krow = bi * 32 + ty + r * 8;
        int ncol = bj * 32 + tx;
        tile[ty + r * 8][tx] = f2bf(W[(size_t)krow * N + ncol]);
    }
    __syncthreads();
#pragma unroll
    for (int r = 0; r < 4; ++r) {
        int nrow = bj * 32 + ty + r * 8;
        int kcol = bi * 32 + tx;
        Wt[(size_t)nrow * K + kcol] = tile[tx][ty + r * 8];
    }
}

// ---------------- per-head V transpose: vT[(b,h)][hd][key] = V[b][key][h][hd] --
__global__ __launch_bounds__(256) void vtrans(const ushort* __restrict__ qkv,
                                              ushort* __restrict__ vT) {
    __shared__ ushort t[64][72];
    const int ktile = blockIdx.x;           // key / 64
    const int bh = blockIdx.y;
    const int b = bh >> 4, h = bh & 15;
    const int tid = threadIdx.x;
    const int r = tid >> 2;                 // 0..63
    const int c0 = (tid & 3) * 16;          // 0,16,32,48
    const ushort* src = qkv + (size_t)(b * LSEQ + ktile * 64 + r) * QKVN + 2048 + h * HDIM + c0;
    union { bf16x8_t v; ushort s[8]; } u0, u1;
    u0.v = *(const bf16x8_t*)src;
    u1.v = *(const bf16x8_t*)(src + 8);
#pragma unroll
    for (int j = 0; j < 8; ++j) { t[r][c0 + j] = u0.s[j]; t[r][c0 + 8 + j] = u1.s[j]; }
    __syncthreads();
    const int hd = tid >> 2;
    union { bf16x8_t v; ushort s[8]; } w0, w1;
#pragma unroll
    for (int j = 0; j < 8; ++j) { w0.s[j] = t[c0 + j][hd]; w1.s[j] = t[c0 + 8 + j][hd]; }
    ushort* dst = vT + (size_t)(bh * HDIM + hd) * LSEQ + ktile * 64 + c0;
    *(bf16x8_t*)dst = w0.v;
    *(bf16x8_t*)(dst + 8) = w1.v;
}

// ---------------- RMSNorm: fp32 in -> bf16 out --------------------------------
__global__ __launch_bounds__(256) void rmsnorm_k(const float* __restrict__ x,
                                                 const float* __restrict__ g,
                                                 ushort* __restrict__ out) {
    int row = blockIdx.x;
    int t = threadIdx.x;
    int w = t >> 6, l = t & 63;
    const float4 v = reinterpret_cast<const float4*>(x + (size_t)row * BDIM)[t];
    float ss = v.x * v.x + v.y * v.y + v.z * v.z + v.w * v.w;
#pragma unroll
    for (int m = 1; m <= 32; m <<= 1) ss += __shfl_xor(ss, m);
    __shared__ float wsum[4];
    if (l == 0) wsum[w] = ss;
    __syncthreads();
    float tot = wsum[0] + wsum[1] + wsum[2] + wsum[3];
    float r = rsqrtf(tot * (1.0f / BDIM) + 1e-6f);
    const float4 gv = reinterpret_cast<const float4*>(g)[t];
    ushort4 o;
    o.x = f2bf(v.x * r * gv.x);
    o.y = f2bf(v.y * r * gv.y);
    o.z = f2bf(v.z * r * gv.z);
    o.w = f2bf(v.w * r * gv.w);
    reinterpret_cast<ushort4*>(out + (size_t)row * BDIM)[t] = o;
}

// ---------------- T5 relative position bias table: btab[h][d], d = k-q+2047 ---
__global__ void bias_table_k(const float* __restrict__ rel, float* __restrict__ btab) {
    int idx = blockIdx.x * 256 + threadIdx.x;
    if (idx >= HEADS * 4095) return;
    int h = idx / 4095;
    int d = idx % 4095;
    int rp = d - 2047;                 // mem - ctx
    int bucket = rp > 0 ? 16 : 0;
    int rpa = rp < 0 ? -rp : rp;
    if (rpa < 8) {
        bucket += rpa;
    } else {
        int large = 8 + (int)(logf((float)rpa * 0.125f) * (1.0f / logf(16.0f)) * 8.0f);
        bucket += large < 15 ? large : 15;
    }
    btab[idx] = rel[bucket * HEADS + h];
}

// ---------------- bf16 GEMM, B pre-transposed (Bt is N x K), 1D grid + XCD swz
// MODE 0: bf16 out = A@B ;  MODE 1: f32 out = res + A@B ;  MODE 2: bf16 out = relu(A@B)
template <int MODE, int TM, int TN>
__global__ __launch_bounds__(256) void gemm_bt(const ushort* __restrict__ A,
                                               const ushort* __restrict__ Bt,
                                               void* Cout, const float* res,
                                               int M, int N, int K, int nbx) {
    __shared__ __align__(16) ushort As[TM * 64];
    __shared__ __align__(16) ushort Bs[TN * 64];
    constexpr int MF = TM / 32, NF = TN / 32;
    const int nwg = gridDim.x;
    const int bid = blockIdx.x;
    const int swz = (bid & 7) * (nwg >> 3) + (bid >> 3);   // nwg % 8 == 0 always
    const int bx = swz % nbx, by = swz / nbx;
    const int tid = threadIdx.x;
    const int w = tid >> 6, l = tid & 63;
    const int wm = w >> 1, wn = w & 1;
    const int rowA0 = by * TM;
    const int colB0 = bx * TN;
    const int lr = l >> 3;
    const int lc = (l & 7) * 8;
    const int c = l & 15, gq = l >> 4;
    f32x4_t acc[MF][NF] = {};

    for (int k0 = 0; k0 < K; k0 += 64) {
        __syncthreads();
#pragma unroll
        for (int i = 0; i < TM / 32; ++i) {
            int r = i * 32 + w * 8;
            __builtin_amdgcn_global_load_lds(
                (const __attribute__((address_space(1))) uint32_t*)(A + (size_t)(rowA0 + r + lr) * K + k0 + lc),
                (__attribute__((address_space(3))) uint32_t*)(&As[r * 64]), 16, 0, 0);
        }
#pragma unroll
        for (int i = 0; i < TN / 32; ++i) {
            int r = i * 32 + w * 8;
            __builtin_amdgcn_global_load_lds(
                (const __attribute__((address_space(1))) uint32_t*)(Bt + (size_t)(colB0 + r + lr) * K + k0 + lc),
                (__attribute__((address_space(3))) uint32_t*)(&Bs[r * 64]), 16, 0, 0);
        }
        __syncthreads();
#pragma unroll
        for (int kk = 0; kk < 2; ++kk) {
            bf16x8_t av[MF], bv[NF];
#pragma unroll
            for (int mf = 0; mf < MF; ++mf)
                av[mf] = *(const bf16x8_t*)&As[(wm * (TM / 2) + mf * 16 + c) * 64 + kk * 32 + gq * 8];
#pragma unroll
            for (int nf = 0; nf < NF; ++nf)
                bv[nf] = *(const bf16x8_t*)&Bs[(wn * (TN / 2) + nf * 16 + c) * 64 + kk * 32 + gq * 8];
#pragma unroll
            for (int mf = 0; mf < MF; ++mf)
#pragma unroll
                for (int nf = 0; nf < NF; ++nf)
                    acc[mf][nf] = __builtin_amdgcn_mfma_f32_16x16x32_bf16(av[mf], bv[nf], acc[mf][nf], 0, 0, 0);
        }
    }
#pragma unroll
    for (int mf = 0; mf < MF; ++mf) {
#pragma unroll
        for (int nf = 0; nf < NF; ++nf) {
#pragma unroll
            for (int i = 0; i < 4; ++i) {
                int row = rowA0 + wm * (TM / 2) + mf * 16 + gq * 4 + i;
                int col = colB0 + wn * (TN / 2) + nf * 16 + c;
                size_t idx = (size_t)row * N + col;
                float vv = acc[mf][nf][i];
                if (MODE == 0) {
                    ((ushort*)Cout)[idx] = f2bf(vv);
                } else if (MODE == 1) {
                    ((float*)Cout)[idx] = res[idx] + vv;
                } else {
                    ((ushort*)Cout)[idx] = f2bf(vv > 0.f ? vv : 0.f);
                }
            }
        }
    }
}

// ---------------- flash attention, swapped-QK^T (lane-local softmax rows) -----
// grid: x = q-tile (L/64), y = b*H + h. block = 256 (4 independent waves x 16 q).
// s = mfma(K_frag, Q_frag) -> S^T[key][q]: lane (c,g) owns q-row q0+c, keys
// {nf*16 + g*4 + i}. Row-reduce = in-lane + shfl_xor(16,32). Same loads as before.
__global__ __launch_bounds__(256, 2) void attn_fwd(const ushort* __restrict__ qkv,
                                                   const ushort* __restrict__ vT,
                                                   const float* __restrict__ btab,
                                                   ushort* __restrict__ ob) {
    const int tid = threadIdx.x, w = tid >> 6, l = tid & 63;
    const int bh = blockIdx.y, b = bh >> 4, h = bh & 15;
    const int qt = blockIdx.x;
    __shared__ __align__(16) ushort Pl[4][16 * 72];    // per-wave P[q][key], stride 72
    const int q0 = qt * 64 + w * 16;
    const int c = l & 15, g = l >> 4;
    const size_t rowbase = (size_t)b * LSEQ * QKVN;
    const ushort* qp = qkv + rowbase + h * HDIM;
    const ushort* kp = qkv + rowbase + BDIM + h * HDIM;
    const ushort* vtp = vT + (size_t)bh * HDIM * LSEQ;
    // bias for (key, q=q0+c): btq4[key0 + nf*16 + i]
    const float* btq4 = btab + h * 4095 + 2047 - (q0 + c) + g * 4;

    bf16x8_t aq[2];  // B-operand: Q[q0+c][kk*32 + g*8 + j]
#pragma unroll
    for (int kk = 0; kk < 2; ++kk)
        aq[kk] = *(const bf16x8_t*)(qp + (size_t)(q0 + c) * QKVN + kk * 32 + g * 8);

    float mrow = -INFINITY, lrow = 0.f;
    f32x4_t o[4] = {};   // O^T[hd = hf*16 + g*4 + i][q0+c]

    bf16x8_t kreg[4][2], vreg[4][2];
    f32x4_t s[4];        // S^T[key0 + nf*16 + g*4 + i][q0+c]

    auto loadK = [&](int key0) {
#pragma unroll
        for (int nf = 0; nf < 4; ++nf)
#pragma unroll
            for (int kk = 0; kk < 2; ++kk)
                kreg[nf][kk] = *(const bf16x8_t*)(kp + (size_t)(key0 + nf * 16 + c) * QKVN + kk * 32 + g * 8);
    };
    auto loadV = [&](int key0) {
#pragma unroll
        for (int hf = 0; hf < 4; ++hf)
#pragma unroll
            for (int kk = 0; kk < 2; ++kk)
                vreg[hf][kk] = *(const bf16x8_t*)(vtp + (size_t)(hf * 16 + c) * LSEQ + key0 + kk * 32 + g * 8);
    };
    auto loadBias = [&](int key0) {
#pragma unroll
        for (int nf = 0; nf < 4; ++nf)
#pragma unroll
            for (int i = 0; i < 4; ++i)
                s[nf][i] = btq4[key0 + nf * 16 + i];
    };

    loadK(0);
    loadV(0);
    loadBias(0);

    ushort* Pw = Pl[w];
    for (int kt = 0; kt < 32; ++kt) {
        const int key0 = kt * 64;
        // 1. S^T = bias + K Q^T (C-in pre-filled with bias)
#pragma unroll
        for (int kk = 0; kk < 2; ++kk)
#pragma unroll
            for (int nf = 0; nf < 4; ++nf)
                s[nf] = __builtin_amdgcn_mfma_f32_16x16x32_bf16(kreg[nf][kk], aq[kk], s[nf], 0, 0, 0);
        // 2. prefetch K(kt+1); pin issue point
        if (kt < 31) loadK(key0 + 64);
        __builtin_amdgcn_sched_barrier(0);
        // 3. softmax: in-lane max over 16 + 2 cross-lane shfl
        float tmax = -INFINITY;
#pragma unroll
        for (int nf = 0; nf < 4; ++nf)
#pragma unroll
            for (int i = 0; i < 4; ++i)
                tmax = fmaxf(tmax, s[nf][i]);
        tmax = fmaxf(tmax, __shfl_xor(tmax, 16));
        tmax = fmaxf(tmax, __shfl_xor(tmax, 32));
        if (!__all(tmax - mrow <= 8.f)) {
            float mn = fmaxf(mrow, tmax);
            float sc = __expf(mrow - mn);
            mrow = mn;
            lrow *= sc;
#pragma unroll
            for (int hf = 0; hf < 4; ++hf) o[hf] *= sc;
        }
        float rs = 0.f;
        union { ushort us[4]; uint2 u2; } pk[4];
#pragma unroll
        for (int nf = 0; nf < 4; ++nf)
#pragma unroll
            for (int i = 0; i < 4; ++i) {
                float pv = __expf(s[nf][i] - mrow);
                rs += pv;
                pk[nf].us[i] = f2bf(pv);
            }
        // 4. prefetch bias(kt+1) into accumulator (s is dead now)
        if (kt < 31) loadBias(key0 + 64);
        rs += __shfl_xor(rs, 16);
        rs += __shfl_xor(rs, 32);
        lrow += rs;
        // 5. P -> per-wave LDS [q=c][key], packed b64 writes; wave-local
#pragma unroll
        for (int nf = 0; nf < 4; ++nf)
            *(uint2*)&Pw[c * 72 + nf * 16 + g * 4] = pk[nf].u2;
        bf16x8_t pa[2];
#pragma unroll
        for (int kk = 0; kk < 2; ++kk)
            pa[kk] = *(const bf16x8_t*)&Pw[c * 72 + kk * 32 + g * 8];
        // 6. O^T += V^T P^T
#pragma unroll
        for (int kk = 0; kk < 2; ++kk)
#pragma unroll
            for (int hf = 0; hf < 4; ++hf)
                o[hf] = __builtin_amdgcn_mfma_f32_16x16x32_bf16(vreg[hf][kk], pa[kk], o[hf], 0, 0, 0);
        // 7. prefetch V(kt+1); pin issue point
        if (kt < 31) loadV(key0 + 64);
        __builtin_amdgcn_sched_barrier(0);
    }
    const float inv = 1.f / lrow;
    ushort* orow = ob + (size_t)(b * LSEQ + q0 + c) * BDIM + h * HDIM + g * 4;
#pragma unroll
    for (int hf = 0; hf < 4; ++hf) {
        ushort4 ov;
        ov.x = f2bf(o[hf][0] * inv);
        ov.y = f2bf(o[hf][1] * inv);
        ov.z = f2bf(o[hf][2] * inv);
        ov.w = f2bf(o[hf][3] * inv);
        *(ushort4*)(orow + hf * 16) = ov;
    }
}

extern "C" void kernel_launch(void* const* d_in, const int* in_sizes, int n_in,
                              void* d_out, int out_size, void* d_ws, size_t ws_size,
                              hipStream_t stream) {
    const float* x   = (const float*)d_in[0];
    const float* Wq  = (const float*)d_in[1];
    const float* Wk  = (const float*)d_in[2];
    const float* Wv  = (const float*)d_in[3];
    const float* Wo  = (const float*)d_in[4];
    const float* W1  = (const float*)d_in[5];
    const float* W2  = (const float*)d_in[6];
    const float* g1  = (const float*)d_in[7];
    const float* g2  = (const float*)d_in[8];
    const float* rel = (const float*)d_in[9];
    float* out = (float*)d_out;

    char* ws = (char*)d_ws;
    const size_t MB = 1024 * 1024;
    ushort* wqkvT = (ushort*)(ws + 0 * MB);    // 3072 x 1024 bf16 = 6MB
    ushort* woT   = (ushort*)(ws + 6 * MB);    // 2MB
    ushort* w1T   = (ushort*)(ws + 8 * MB);    // 4096 x 1024 = 8MB
    ushort* w2T   = (ushort*)(ws + 16 * MB);   // 1024 x 4096 = 8MB
    float*  btab  = (float*)(ws + 24 * MB);    // 256KB
    ushort* hbuf  = (ushort*)(ws + 25 * MB);   // 8MB: h, then attn_out, then h2
    ushort* qkvb  = (ushort*)(ws + 33 * MB);   // 4096 x 3072 = 24MB
    ushort* f1b   = (ushort*)(ws + 33 * MB);   // 32MB, reuses qkv+vT after attn
    ushort* vTb   = (ushort*)(ws + 57 * MB);   // 8MB; total 65MB
    (void)in_sizes; (void)n_in; (void)out_size; (void)ws_size;

    dim3 tb(32, 8);
    transpose_cvt<<<dim3(32, 32),  tb, 0, stream>>>(Wq, wqkvT,                1024, 1024);
    transpose_cvt<<<dim3(32, 32),  tb, 0, stream>>>(Wk, wqkvT + 1024 * 1024,  1024, 1024);
    transpose_cvt<<<dim3(32, 32),  tb, 0, stream>>>(Wv, wqkvT + 2048 * 1024,  1024, 1024);
    transpose_cvt<<<dim3(32, 32),  tb, 0, stream>>>(Wo, woT, 1024, 1024);
    transpose_cvt<<<dim3(128, 32), tb, 0, stream>>>(W1, w1T, 1024, 4096);
    transpose_cvt<<<dim3(32, 128), tb, 0, stream>>>(W2, w2T, 4096, 1024);
    bias_table_k<<<256, 256, 0, stream>>>(rel, btab);

    rmsnorm_k<<<4096, 256, 0, stream>>>(x, g1, hbuf);
    gemm_bt<0, 128, 128><<<768, 256, 0, stream>>>(hbuf, wqkvT, qkvb, nullptr, 4096, QKVN, 1024, 24);
    vtrans<<<dim3(32, 32), 256, 0, stream>>>(qkvb, vTb);
    attn_fwd<<<dim3(32, 32), 256, 0, stream>>>(qkvb, vTb, btab, hbuf);
    gemm_bt<1, 128, 64><<<512, 256, 0, stream>>>(hbuf, woT, out, x, 4096, 1024, 1024, 16);
    rmsnorm_k<<<4096, 256, 0, stream>>>(out, g2, hbuf);
    gemm_bt<2, 128, 128><<<1024, 256, 0, stream>>>(hbuf, w1T, f1b, nullptr, 4096, DFFDIM, 1024, 32);
    gemm_bt<1, 128, 64><<<512, 256, 0, stream>>>(f1b, w2T, out, out, 4096, 1024, DFFDIM, 16);
}

// Round 5
// 351.186 us; speedup vs baseline: 1.5679x; 1.4108x over previous
//
#include <hip/hip_runtime.h>
#include <hip/hip_bf16.h>
#include <math.h>

#define BDIM 1024
#define HEADS 16
#define HDIM 64
#define LSEQ 2048
#define NBATCH 2
#define DFFDIM 4096
#define QKVN 3072

typedef __bf16 bf16x8_t __attribute__((ext_vector_type(8)));
typedef float f32x4_t __attribute__((ext_vector_type(4)));

__device__ __forceinline__ ushort f2bf(float f) {
    union { __hip_bfloat16 b; ushort u; } cv;
    cv.b = __float2bfloat16(f);
    return cv.u;
}

// ---------------- transpose + fp32->bf16 convert: Wt[n][k] = bf16(W[k][n]) ----
__global__ __launch_bounds__(256) void transpose_cvt(const float* __restrict__ W,
                                                     ushort* __restrict__ Wt,
                                                     int K, int N) {
    __shared__ ushort tile[32][33];
    int bi = blockIdx.y;   // K / 32
    int bj = blockIdx.x;   // N / 32
    int tx = threadIdx.x;  // 32
    int ty = threadIdx.y;  // 8
#pragma unroll
    for (int r = 0; r < 4; ++r) {
        int krow = bi * 32 + ty + r * 8;
        int ncol = bj * 32 + tx;
        tile[ty + r * 8][tx] = f2bf(W[(size_t)krow * N + ncol]);
    }
    __syncthreads();
#pragma unroll
    for (int r = 0; r < 4; ++r) {
        int nrow = bj * 32 + ty + r * 8;
        int kcol = bi * 32 + tx;
        Wt[(size_t)nrow * K + kcol] = tile[tx][ty + r * 8];
    }
}

// ---------------- per-head V transpose: vT[(b,h)][hd][key] = V[b][key][h][hd] --
__global__ __launch_bounds__(256) void vtrans(const ushort* __restrict__ qkv,
                                              ushort* __restrict__ vT) {
    __shared__ ushort t[64][72];
    const int ktile = blockIdx.x;           // key / 64
    const int bh = blockIdx.y;
    const int b = bh >> 4, h = bh & 15;
    const int tid = threadIdx.x;
    const int r = tid >> 2;                 // 0..63
    const int c0 = (tid & 3) * 16;          // 0,16,32,48
    const ushort* src = qkv + (size_t)(b * LSEQ + ktile * 64 + r) * QKVN + 2048 + h * HDIM + c0;
    union { bf16x8_t v; ushort s[8]; } u0, u1;
    u0.v = *(const bf16x8_t*)src;
    u1.v = *(const bf16x8_t*)(src + 8);
#pragma unroll
    for (int j = 0; j < 8; ++j) { t[r][c0 + j] = u0.s[j]; t[r][c0 + 8 + j] = u1.s[j]; }
    __syncthreads();
    const int hd = tid >> 2;
    union { bf16x8_t v; ushort s[8]; } w0, w1;
#pragma unroll
    for (int j = 0; j < 8; ++j) { w0.s[j] = t[c0 + j][hd]; w1.s[j] = t[c0 + 8 + j][hd]; }
    ushort* dst = vT + (size_t)(bh * HDIM + hd) * LSEQ + ktile * 64 + c0;
    *(bf16x8_t*)dst = w0.v;
    *(bf16x8_t*)(dst + 8) = w1.v;
}

// ---------------- RMSNorm: fp32 in -> bf16 out --------------------------------
__global__ __launch_bounds__(256) void rmsnorm_k(const float* __restrict__ x,
                                                 const float* __restrict__ g,
                                                 ushort* __restrict__ out) {
    int row = blockIdx.x;
    int t = threadIdx.x;
    int w = t >> 6, l = t & 63;
    const float4 v = reinterpret_cast<const float4*>(x + (size_t)row * BDIM)[t];
    float ss = v.x * v.x + v.y * v.y + v.z * v.z + v.w * v.w;
#pragma unroll
    for (int m = 1; m <= 32; m <<= 1) ss += __shfl_xor(ss, m);
    __shared__ float wsum[4];
    if (l == 0) wsum[w] = ss;
    __syncthreads();
    float tot = wsum[0] + wsum[1] + wsum[2] + wsum[3];
    float r = rsqrtf(tot * (1.0f / BDIM) + 1e-6f);
    const float4 gv = reinterpret_cast<const float4*>(g)[t];
    ushort4 o;
    o.x = f2bf(v.x * r * gv.x);
    o.y = f2bf(v.y * r * gv.y);
    o.z = f2bf(v.z * r * gv.z);
    o.w = f2bf(v.w * r * gv.w);
    reinterpret_cast<ushort4*>(out + (size_t)row * BDIM)[t] = o;
}

// ---------------- T5 relative position bias table: btab[h][d], d = k-q+2047 ---
__global__ void bias_table_k(const float* __restrict__ rel, float* __restrict__ btab) {
    int idx = blockIdx.x * 256 + threadIdx.x;
    if (idx >= HEADS * 4095) return;
    int h = idx / 4095;
    int d = idx % 4095;
    int rp = d - 2047;                 // mem - ctx
    int bucket = rp > 0 ? 16 : 0;
    int rpa = rp < 0 ? -rp : rp;
    if (rpa < 8) {
        bucket += rpa;
    } else {
        int large = 8 + (int)(logf((float)rpa * 0.125f) * (1.0f / logf(16.0f)) * 8.0f);
        bucket += large < 15 ? large : 15;
    }
    btab[idx] = rel[bucket * HEADS + h];
}

// ---------------- bf16 GEMM, B pre-transposed (Bt is N x K), 1D grid + XCD swz
// MODE 0: bf16 out = A@B ;  MODE 1: f32 out = res + A@B ;  MODE 2: bf16 out = relu(A@B)
template <int MODE, int TM, int TN>
__global__ __launch_bounds__(256) void gemm_bt(const ushort* __restrict__ A,
                                               const ushort* __restrict__ Bt,
                                               void* Cout, const float* res,
                                               int M, int N, int K, int nbx) {
    __shared__ __align__(16) ushort As[TM * 64];
    __shared__ __align__(16) ushort Bs[TN * 64];
    constexpr int MF = TM / 32, NF = TN / 32;
    const int nwg = gridDim.x;
    const int bid = blockIdx.x;
    const int swz = (bid & 7) * (nwg >> 3) + (bid >> 3);   // nwg % 8 == 0 always
    const int bx = swz % nbx, by = swz / nbx;
    const int tid = threadIdx.x;
    const int w = tid >> 6, l = tid & 63;
    const int wm = w >> 1, wn = w & 1;
    const int rowA0 = by * TM;
    const int colB0 = bx * TN;
    const int lr = l >> 3;
    const int lc = (l & 7) * 8;
    const int c = l & 15, gq = l >> 4;
    f32x4_t acc[MF][NF] = {};

    for (int k0 = 0; k0 < K; k0 += 64) {
        __syncthreads();
#pragma unroll
        for (int i = 0; i < TM / 32; ++i) {
            int r = i * 32 + w * 8;
            __builtin_amdgcn_global_load_lds(
                (const __attribute__((address_space(1))) uint32_t*)(A + (size_t)(rowA0 + r + lr) * K + k0 + lc),
                (__attribute__((address_space(3))) uint32_t*)(&As[r * 64]), 16, 0, 0);
        }
#pragma unroll
        for (int i = 0; i < TN / 32; ++i) {
            int r = i * 32 + w * 8;
            __builtin_amdgcn_global_load_lds(
                (const __attribute__((address_space(1))) uint32_t*)(Bt + (size_t)(colB0 + r + lr) * K + k0 + lc),
                (__attribute__((address_space(3))) uint32_t*)(&Bs[r * 64]), 16, 0, 0);
        }
        __syncthreads();
#pragma unroll
        for (int kk = 0; kk < 2; ++kk) {
            bf16x8_t av[MF], bv[NF];
#pragma unroll
            for (int mf = 0; mf < MF; ++mf)
                av[mf] = *(const bf16x8_t*)&As[(wm * (TM / 2) + mf * 16 + c) * 64 + kk * 32 + gq * 8];
#pragma unroll
            for (int nf = 0; nf < NF; ++nf)
                bv[nf] = *(const bf16x8_t*)&Bs[(wn * (TN / 2) + nf * 16 + c) * 64 + kk * 32 + gq * 8];
#pragma unroll
            for (int mf = 0; mf < MF; ++mf)
#pragma unroll
                for (int nf = 0; nf < NF; ++nf)
                    acc[mf][nf] = __builtin_amdgcn_mfma_f32_16x16x32_bf16(av[mf], bv[nf], acc[mf][nf], 0, 0, 0);
        }
    }
#pragma unroll
    for (int mf = 0; mf < MF; ++mf) {
#pragma unroll
        for (int nf = 0; nf < NF; ++nf) {
#pragma unroll
            for (int i = 0; i < 4; ++i) {
                int row = rowA0 + wm * (TM / 2) + mf * 16 + gq * 4 + i;
                int col = colB0 + wn * (TN / 2) + nf * 16 + c;
                size_t idx = (size_t)row * N + col;
                float vv = acc[mf][nf][i];
                if (MODE == 0) {
                    ((ushort*)Cout)[idx] = f2bf(vv);
                } else if (MODE == 1) {
                    ((float*)Cout)[idx] = res[idx] + vv;
                } else {
                    ((ushort*)Cout)[idx] = f2bf(vv > 0.f ? vv : 0.f);
                }
            }
        }
    }
}

// ---------------- flash attention, LDS-staged K/V (m97 2-barrier structure) ---
// grid: x = q-tile (L/64), y = b*H + h. block = 256 (4 waves x 16 q-rows).
// All 4 waves share the same K-tile and V-tile -> stage both via
// global_load_lds (zero VGPR cost), compute frags from LDS like gemm_bt.
// Swapped QK^T: s = mfma(K,Q) so each lane owns one q-row (lane-local softmax).
__global__ __launch_bounds__(256) void attn_fwd(const ushort* __restrict__ qkv,
                                                const ushort* __restrict__ vT,
                                                const float* __restrict__ btab,
                                                ushort* __restrict__ ob) {
    const int tid = threadIdx.x, w = tid >> 6, l = tid & 63;
    const int bh = blockIdx.y, b = bh >> 4, h = bh & 15;
    const int qt = blockIdx.x;
    __shared__ __align__(16) ushort Ks[64 * 64];       // [key][hd]
    __shared__ __align__(16) ushort Vs[64 * 64];       // [hd][key-key0]
    __shared__ __align__(16) ushort Pl[4][16 * 72];    // per-wave P[q][key], stride 72
    const int q0 = qt * 64 + w * 16;
    const int c = l & 15, g = l >> 4;
    const size_t rowbase = (size_t)b * LSEQ * QKVN;
    const ushort* qp = qkv + rowbase + h * HDIM;
    const ushort* kp = qkv + rowbase + BDIM + h * HDIM;
    const ushort* vtp = vT + (size_t)bh * HDIM * LSEQ;
    // staging: chunk = i*256 + tid covers LDS byte chunk*16; row = i*32+w*8+(l>>3)
    const int sr = w * 8 + (l >> 3);       // staging row within 32-row half
    const int sc = (l & 7) * 8;            // staging col (ushorts)
    // bias for (key, q=q0+c): btq4[key0 + nf*16 + i]
    const float* btq4 = btab + h * 4095 + 2047 - (q0 + c) + g * 4;

    bf16x8_t aq[2];  // B-operand: Q[q0+c][kk*32 + g*8 + j]
#pragma unroll
    for (int kk = 0; kk < 2; ++kk)
        aq[kk] = *(const bf16x8_t*)(qp + (size_t)(q0 + c) * QKVN + kk * 32 + g * 8);

    float mrow = -INFINITY, lrow = 0.f;
    f32x4_t o[4] = {};   // O^T[hd = hf*16 + g*4 + i][q0+c]
    f32x4_t s[4];        // S^T[key0 + nf*16 + g*4 + i][q0+c]

    auto loadBias = [&](int key0) {
#pragma unroll
        for (int nf = 0; nf < 4; ++nf)
#pragma unroll
            for (int i = 0; i < 4; ++i)
                s[nf][i] = btq4[key0 + nf * 16 + i];
    };
    loadBias(0);

    ushort* Pw = Pl[w];
    for (int kt = 0; kt < 32; ++kt) {
        const int key0 = kt * 64;
        __syncthreads();   // safe to overwrite Ks/Vs
        // stage K tile [64 keys][64 hd] and V^T tile [64 hd][64 keys]
#pragma unroll
        for (int i = 0; i < 2; ++i) {
            __builtin_amdgcn_global_load_lds(
                (const __attribute__((address_space(1))) uint32_t*)(kp + (size_t)(key0 + i * 32 + sr) * QKVN + sc),
                (__attribute__((address_space(3))) uint32_t*)(&Ks[(i * 32 + w * 8) * 64]), 16, 0, 0);
            __builtin_amdgcn_global_load_lds(
                (const __attribute__((address_space(1))) uint32_t*)(vtp + (size_t)(i * 32 + sr) * LSEQ + key0 + sc),
                (__attribute__((address_space(3))) uint32_t*)(&Vs[(i * 32 + w * 8) * 64]), 16, 0, 0);
        }
        __syncthreads();   // vmcnt drain: staged tiles visible to all waves
        // 1. S^T = bias + K Q^T
#pragma unroll
        for (int kk = 0; kk < 2; ++kk)
#pragma unroll
            for (int nf = 0; nf < 4; ++nf) {
                bf16x8_t kf = *(const bf16x8_t*)&Ks[(nf * 16 + c) * 64 + kk * 32 + g * 8];
                s[nf] = __builtin_amdgcn_mfma_f32_16x16x32_bf16(kf, aq[kk], s[nf], 0, 0, 0);
            }
        // 2. softmax: in-lane max over 16 + 2 cross-lane shfl
        float tmax = -INFINITY;
#pragma unroll
        for (int nf = 0; nf < 4; ++nf)
#pragma unroll
            for (int i = 0; i < 4; ++i)
                tmax = fmaxf(tmax, s[nf][i]);
        tmax = fmaxf(tmax, __shfl_xor(tmax, 16));
        tmax = fmaxf(tmax, __shfl_xor(tmax, 32));
        if (!__all(tmax - mrow <= 8.f)) {
            float mn = fmaxf(mrow, tmax);
            float sc2 = __expf(mrow - mn);
            mrow = mn;
            lrow *= sc2;
#pragma unroll
            for (int hf = 0; hf < 4; ++hf) o[hf] *= sc2;
        }
        float rs = 0.f;
        union { ushort us[4]; uint2 u2; } pk[4];
#pragma unroll
        for (int nf = 0; nf < 4; ++nf)
#pragma unroll
            for (int i = 0; i < 4; ++i) {
                float pv = __expf(s[nf][i] - mrow);
                rs += pv;
                pk[nf].us[i] = f2bf(pv);
            }
        // 3. prefetch bias(kt+1) into accumulator (s is dead now; L1-resident)
        if (kt < 31) loadBias(key0 + 64);
        rs += __shfl_xor(rs, 16);
        rs += __shfl_xor(rs, 32);
        lrow += rs;
        // 4. P -> per-wave LDS [q=c][key], packed b64 writes; wave-local
#pragma unroll
        for (int nf = 0; nf < 4; ++nf)
            *(uint2*)&Pw[c * 72 + nf * 16 + g * 4] = pk[nf].u2;
        bf16x8_t pa[2];
#pragma unroll
        for (int kk = 0; kk < 2; ++kk)
            pa[kk] = *(const bf16x8_t*)&Pw[c * 72 + kk * 32 + g * 8];
        // 5. O^T += V^T P^T
#pragma unroll
        for (int kk = 0; kk < 2; ++kk)
#pragma unroll
            for (int hf = 0; hf < 4; ++hf) {
                bf16x8_t vf = *(const bf16x8_t*)&Vs[(hf * 16 + c) * 64 + kk * 32 + g * 8];
                o[hf] = __builtin_amdgcn_mfma_f32_16x16x32_bf16(vf, pa[kk], o[hf], 0, 0, 0);
            }
    }
    const float inv = 1.f / lrow;
    ushort* orow = ob + (size_t)(b * LSEQ + q0 + c) * BDIM + h * HDIM + g * 4;
#pragma unroll
    for (int hf = 0; hf < 4; ++hf) {
        ushort4 ov;
        ov.x = f2bf(o[hf][0] * inv);
        ov.y = f2bf(o[hf][1] * inv);
        ov.z = f2bf(o[hf][2] * inv);
        ov.w = f2bf(o[hf][3] * inv);
        *(ushort4*)(orow + hf * 16) = ov;
    }
}

extern "C" void kernel_launch(void* const* d_in, const int* in_sizes, int n_in,
                              void* d_out, int out_size, void* d_ws, size_t ws_size,
                              hipStream_t stream) {
    const float* x   = (const float*)d_in[0];
    const float* Wq  = (const float*)d_in[1];
    const float* Wk  = (const float*)d_in[2];
    const float* Wv  = (const float*)d_in[3];
    const float* Wo  = (const float*)d_in[4];
    const float* W1  = (const float*)d_in[5];
    const float* W2  = (const float*)d_in[6];
    const float* g1  = (const float*)d_in[7];
    const float* g2  = (const float*)d_in[8];
    const float* rel = (const float*)d_in[9];
    float* out = (float*)d_out;

    char* ws = (char*)d_ws;
    const size_t MB = 1024 * 1024;
    ushort* wqkvT = (ushort*)(ws + 0 * MB);    // 3072 x 1024 bf16 = 6MB
    ushort* woT   = (ushort*)(ws + 6 * MB);    // 2MB
    ushort* w1T   = (ushort*)(ws + 8 * MB);    // 4096 x 1024 = 8MB
    ushort* w2T   = (ushort*)(ws + 16 * MB);   // 1024 x 4096 = 8MB
    float*  btab  = (float*)(ws + 24 * MB);    // 256KB
    ushort* hbuf  = (ushort*)(ws + 25 * MB);   // 8MB: h, then attn_out, then h2
    ushort* qkvb  = (ushort*)(ws + 33 * MB);   // 4096 x 3072 = 24MB
    ushort* f1b   = (ushort*)(ws + 33 * MB);   // 32MB, reuses qkv+vT after attn
    ushort* vTb   = (ushort*)(ws + 57 * MB);   // 8MB; total 65MB
    (void)in_sizes; (void)n_in; (void)out_size; (void)ws_size;

    dim3 tb(32, 8);
    transpose_cvt<<<dim3(32, 32),  tb, 0, stream>>>(Wq, wqkvT,                1024, 1024);
    transpose_cvt<<<dim3(32, 32),  tb, 0, stream>>>(Wk, wqkvT + 1024 * 1024,  1024, 1024);
    transpose_cvt<<<dim3(32, 32),  tb, 0, stream>>>(Wv, wqkvT + 2048 * 1024,  1024, 1024);
    transpose_cvt<<<dim3(32, 32),  tb, 0, stream>>>(Wo, woT, 1024, 1024);
    transpose_cvt<<<dim3(128, 32), tb, 0, stream>>>(W1, w1T, 1024, 4096);
    transpose_cvt<<<dim3(32, 128), tb, 0, stream>>>(W2, w2T, 4096, 1024);
    bias_table_k<<<256, 256, 0, stream>>>(rel, btab);

    rmsnorm_k<<<4096, 256, 0, stream>>>(x, g1, hbuf);
    gemm_bt<0, 128, 128><<<768, 256, 0, stream>>>(hbuf, wqkvT, qkvb, nullptr, 4096, QKVN, 1024, 24);
    vtrans<<<dim3(32, 32), 256, 0, stream>>>(qkvb, vTb);
    attn_fwd<<<dim3(32, 32), 256, 0, stream>>>(qkvb, vTb, btab, hbuf);
    gemm_bt<1, 128, 64><<<512, 256, 0, stream>>>(hbuf, woT, out, x, 4096, 1024, 1024, 16);
    rmsnorm_k<<<4096, 256, 0, stream>>>(out, g2, hbuf);
    gemm_bt<2, 128, 128><<<1024, 256, 0, stream>>>(hbuf, w1T, f1b, nullptr, 4096, DFFDIM, 1024, 32);
    gemm_bt<1, 128, 64><<<512, 256, 0, stream>>>(f1b, w2T, out, out, 4096, 1024, DFFDIM, 16);
}

// Round 6
// 345.044 us; speedup vs baseline: 1.5958x; 1.0178x over previous
//
#include <hip/hip_runtime.h>
#include <hip/hip_bf16.h>
#include <math.h>

#define BDIM 1024
#define HEADS 16
#define HDIM 64
#define LSEQ 2048
#define NBATCH 2
#define DFFDIM 4096
#define QKVN 3072

typedef __bf16 bf16x8_t __attribute__((ext_vector_type(8)));
typedef float f32x4_t __attribute__((ext_vector_type(4)));

__device__ __forceinline__ ushort f2bf(float f) {
    union { __hip_bfloat16 b; ushort u; } cv;
    cv.b = __float2bfloat16(f);
    return cv.u;
}

// ---------------- transpose + fp32->bf16 convert: Wt[n][k] = bf16(W[k][n]) ----
__global__ __launch_bounds__(256) void transpose_cvt(const float* __restrict__ W,
                                                     ushort* __restrict__ Wt,
                                                     int K, int N) {
    __shared__ ushort tile[32][33];
    int bi = blockIdx.y;   // K / 32
    int bj = blockIdx.x;   // N / 32
    int tx = threadIdx.x;  // 32
    int ty = threadIdx.y;  // 8
#pragma unroll
    for (int r = 0; r < 4; ++r) {
        int krow = bi * 32 + ty + r * 8;
        int ncol = bj * 32 + tx;
        tile[ty + r * 8][tx] = f2bf(W[(size_t)krow * N + ncol]);
    }
    __syncthreads();
#pragma unroll
    for (int r = 0; r < 4; ++r) {
        int nrow = bj * 32 + ty + r * 8;
        int kcol = bi * 32 + tx;
        Wt[(size_t)nrow * K + kcol] = tile[tx][ty + r * 8];
    }
}

// ---------------- per-head V transpose: vT[(b,h)][hd][key] = V[b][key][h][hd] --
__global__ __launch_bounds__(256) void vtrans(const ushort* __restrict__ qkv,
                                              ushort* __restrict__ vT) {
    __shared__ ushort t[64][72];
    const int ktile = blockIdx.x;           // key / 64
    const int bh = blockIdx.y;
    const int b = bh >> 4, h = bh & 15;
    const int tid = threadIdx.x;
    const int r = tid >> 2;                 // 0..63
    const int c0 = (tid & 3) * 16;          // 0,16,32,48
    const ushort* src = qkv + (size_t)(b * LSEQ + ktile * 64 + r) * QKVN + 2048 + h * HDIM + c0;
    union { bf16x8_t v; ushort s[8]; } u0, u1;
    u0.v = *(const bf16x8_t*)src;
    u1.v = *(const bf16x8_t*)(src + 8);
#pragma unroll
    for (int j = 0; j < 8; ++j) { t[r][c0 + j] = u0.s[j]; t[r][c0 + 8 + j] = u1.s[j]; }
    __syncthreads();
    const int hd = tid >> 2;
    union { bf16x8_t v; ushort s[8]; } w0, w1;
#pragma unroll
    for (int j = 0; j < 8; ++j) { w0.s[j] = t[c0 + j][hd]; w1.s[j] = t[c0 + 8 + j][hd]; }
    ushort* dst = vT + (size_t)(bh * HDIM + hd) * LSEQ + ktile * 64 + c0;
    *(bf16x8_t*)dst = w0.v;
    *(bf16x8_t*)(dst + 8) = w1.v;
}

// ---------------- RMSNorm: fp32 in -> bf16 out --------------------------------
__global__ __launch_bounds__(256) void rmsnorm_k(const float* __restrict__ x,
                                                 const float* __restrict__ g,
                                                 ushort* __restrict__ out) {
    int row = blockIdx.x;
    int t = threadIdx.x;
    int w = t >> 6, l = t & 63;
    const float4 v = reinterpret_cast<const float4*>(x + (size_t)row * BDIM)[t];
    float ss = v.x * v.x + v.y * v.y + v.z * v.z + v.w * v.w;
#pragma unroll
    for (int m = 1; m <= 32; m <<= 1) ss += __shfl_xor(ss, m);
    __shared__ float wsum[4];
    if (l == 0) wsum[w] = ss;
    __syncthreads();
    float tot = wsum[0] + wsum[1] + wsum[2] + wsum[3];
    float r = rsqrtf(tot * (1.0f / BDIM) + 1e-6f);
    const float4 gv = reinterpret_cast<const float4*>(g)[t];
    ushort4 o;
    o.x = f2bf(v.x * r * gv.x);
    o.y = f2bf(v.y * r * gv.y);
    o.z = f2bf(v.z * r * gv.z);
    o.w = f2bf(v.w * r * gv.w);
    reinterpret_cast<ushort4*>(out + (size_t)row * BDIM)[t] = o;
}

// ---------------- T5 relative position bias table: btab[h][d], d = k-q+2047 ---
__global__ void bias_table_k(const float* __restrict__ rel, float* __restrict__ btab) {
    int idx = blockIdx.x * 256 + threadIdx.x;
    if (idx >= HEADS * 4095) return;
    int h = idx / 4095;
    int d = idx % 4095;
    int rp = d - 2047;                 // mem - ctx
    int bucket = rp > 0 ? 16 : 0;
    int rpa = rp < 0 ? -rp : rp;
    if (rpa < 8) {
        bucket += rpa;
    } else {
        int large = 8 + (int)(logf((float)rpa * 0.125f) * (1.0f / logf(16.0f)) * 8.0f);
        bucket += large < 15 ? large : 15;
    }
    btab[idx] = rel[bucket * HEADS + h];
}

// ---------------- bf16 GEMM, B pre-transposed (Bt is N x K), 1D grid + XCD swz
// MODE 0: bf16 out = A@B ;  MODE 1: f32 out = res + A@B ;  MODE 2: bf16 out = relu(A@B)
template <int MODE, int TM, int TN>
__global__ __launch_bounds__(256) void gemm_bt(const ushort* __restrict__ A,
                                               const ushort* __restrict__ Bt,
                                               void* Cout, const float* res,
                                               int M, int N, int K, int nbx) {
    __shared__ __align__(16) ushort As[TM * 64];
    __shared__ __align__(16) ushort Bs[TN * 64];
    constexpr int MF = TM / 32, NF = TN / 32;
    const int nwg = gridDim.x;
    const int bid = blockIdx.x;
    const int swz = (bid & 7) * (nwg >> 3) + (bid >> 3);   // nwg % 8 == 0 always
    const int bx = swz % nbx, by = swz / nbx;
    const int tid = threadIdx.x;
    const int w = tid >> 6, l = tid & 63;
    const int wm = w >> 1, wn = w & 1;
    const int rowA0 = by * TM;
    const int colB0 = bx * TN;
    const int lr = l >> 3;
    const int lc = (l & 7) * 8;
    const int c = l & 15, gq = l >> 4;
    f32x4_t acc[MF][NF] = {};

    for (int k0 = 0; k0 < K; k0 += 64) {
        __syncthreads();
#pragma unroll
        for (int i = 0; i < TM / 32; ++i) {
            int r = i * 32 + w * 8;
            __builtin_amdgcn_global_load_lds(
                (const __attribute__((address_space(1))) uint32_t*)(A + (size_t)(rowA0 + r + lr) * K + k0 + lc),
                (__attribute__((address_space(3))) uint32_t*)(&As[r * 64]), 16, 0, 0);
        }
#pragma unroll
        for (int i = 0; i < TN / 32; ++i) {
            int r = i * 32 + w * 8;
            __builtin_amdgcn_global_load_lds(
                (const __attribute__((address_space(1))) uint32_t*)(Bt + (size_t)(colB0 + r + lr) * K + k0 + lc),
                (__attribute__((address_space(3))) uint32_t*)(&Bs[r * 64]), 16, 0, 0);
        }
        __syncthreads();
#pragma unroll
        for (int kk = 0; kk < 2; ++kk) {
            bf16x8_t av[MF], bv[NF];
#pragma unroll
            for (int mf = 0; mf < MF; ++mf)
                av[mf] = *(const bf16x8_t*)&As[(wm * (TM / 2) + mf * 16 + c) * 64 + kk * 32 + gq * 8];
#pragma unroll
            for (int nf = 0; nf < NF; ++nf)
                bv[nf] = *(const bf16x8_t*)&Bs[(wn * (TN / 2) + nf * 16 + c) * 64 + kk * 32 + gq * 8];
#pragma unroll
            for (int mf = 0; mf < MF; ++mf)
#pragma unroll
                for (int nf = 0; nf < NF; ++nf)
                    acc[mf][nf] = __builtin_amdgcn_mfma_f32_16x16x32_bf16(av[mf], bv[nf], acc[mf][nf], 0, 0, 0);
        }
    }
#pragma unroll
    for (int mf = 0; mf < MF; ++mf) {
#pragma unroll
        for (int nf = 0; nf < NF; ++nf) {
#pragma unroll
            for (int i = 0; i < 4; ++i) {
                int row = rowA0 + wm * (TM / 2) + mf * 16 + gq * 4 + i;
                int col = colB0 + wn * (TN / 2) + nf * 16 + c;
                size_t idx = (size_t)row * N + col;
                float vv = acc[mf][nf][i];
                if (MODE == 0) {
                    ((ushort*)Cout)[idx] = f2bf(vv);
                } else if (MODE == 1) {
                    ((float*)Cout)[idx] = res[idx] + vv;
                } else {
                    ((ushort*)Cout)[idx] = f2bf(vv > 0.f ? vv : 0.f);
                }
            }
        }
    }
}

// ---------------- flash attention: LDS dbuf + swizzled K/V, 1 barrier/iter ----
// grid: x = q-tile (L/64), y = b*H + h. block = 256 (4 waves x 16 q-rows).
// K/V tiles staged via global_load_lds with PRE-SWIZZLED global source column
// (LDS dest linear); frag reads XOR col with (row&7)<<3 -> conflict-free b128.
// Double-buffered: barrier; issue stage(kt+1 -> buf^1); compute(buf).
__global__ __launch_bounds__(256) void attn_fwd(const ushort* __restrict__ qkv,
                                                const ushort* __restrict__ vT,
                                                const float* __restrict__ btab,
                                                ushort* __restrict__ ob) {
    const int tid = threadIdx.x, w = tid >> 6, l = tid & 63;
    const int bh = blockIdx.y, b = bh >> 4, h = bh & 15;
    const int qt = blockIdx.x;
    __shared__ __align__(16) ushort Ks[2][64 * 64];    // [key][hd ^ swz]
    __shared__ __align__(16) ushort Vs[2][64 * 64];    // [hd][key ^ swz]
    __shared__ __align__(16) ushort Pl[4][16 * 72];    // per-wave P[q][key], stride 72
    const int q0 = qt * 64 + w * 16;
    const int c = l & 15, g = l >> 4;
    const size_t rowbase = (size_t)b * LSEQ * QKVN;
    const ushort* qp = qkv + rowbase + h * HDIM;
    const ushort* kp = qkv + rowbase + BDIM + h * HDIM;
    const ushort* vtp = vT + (size_t)bh * HDIM * LSEQ;
    // staging: lane covers LDS row sr, 16B chunk (l&7); source col pre-swizzled
    const int sr = w * 8 + (l >> 3);             // row within 32-row half
    const int scs = ((l & 7) ^ (l >> 3)) * 8;    // swizzled source col (ushorts)
    // bias for (key, q=q0+c): btq4[key0 + nf*16 + i]
    const float* btq4 = btab + h * 4095 + 2047 - (q0 + c) + g * 4;

    bf16x8_t aq[2];  // B-operand: Q[q0+c][kk*32 + g*8 + j]
#pragma unroll
    for (int kk = 0; kk < 2; ++kk)
        aq[kk] = *(const bf16x8_t*)(qp + (size_t)(q0 + c) * QKVN + kk * 32 + g * 8);

    float mrow = -INFINITY, lrow = 0.f;
    f32x4_t o[4] = {};   // O^T[hd = hf*16 + g*4 + i][q0+c]
    f32x4_t s[4];        // S^T[key0 + nf*16 + g*4 + i][q0+c]

    auto stage = [&](int buf, int key0) {
#pragma unroll
        for (int i = 0; i < 2; ++i) {
            __builtin_amdgcn_global_load_lds(
                (const __attribute__((address_space(1))) uint32_t*)(kp + (size_t)(key0 + i * 32 + sr) * QKVN + scs),
                (__attribute__((address_space(3))) uint32_t*)(&Ks[buf][(i * 32 + w * 8) * 64]), 16, 0, 0);
            __builtin_amdgcn_global_load_lds(
                (const __attribute__((address_space(1))) uint32_t*)(vtp + (size_t)(i * 32 + sr) * LSEQ + key0 + scs),
                (__attribute__((address_space(3))) uint32_t*)(&Vs[buf][(i * 32 + w * 8) * 64]), 16, 0, 0);
        }
    };
    auto loadBias = [&](int key0) {
#pragma unroll
        for (int nf = 0; nf < 4; ++nf)
#pragma unroll
            for (int i = 0; i < 4; ++i)
                s[nf][i] = btq4[key0 + nf * 16 + i];
    };

    stage(0, 0);
    loadBias(0);
    int cur = 0;

    ushort* Pw = Pl[w];
    const int rswz = (c & 7) << 3;   // read-side XOR for rows nf*16+c / hf*16+c
    for (int kt = 0; kt < 32; ++kt) {
        __syncthreads();   // buf[cur] staged (vmcnt drained at barrier); buf[cur^1] free
        // issue next tile's stage NOW -> latency hidden under compute below
        if (kt < 31) stage(cur ^ 1, kt * 64 + 64);
        // 1. S^T = bias + K Q^T
#pragma unroll
        for (int kk = 0; kk < 2; ++kk)
#pragma unroll
            for (int nf = 0; nf < 4; ++nf) {
                bf16x8_t kf = *(const bf16x8_t*)&Ks[cur][(nf * 16 + c) * 64 + ((kk * 32 + g * 8) ^ rswz)];
                s[nf] = __builtin_amdgcn_mfma_f32_16x16x32_bf16(kf, aq[kk], s[nf], 0, 0, 0);
            }
        // 2. softmax: in-lane max over 16 + 2 cross-lane shfl
        float tmax = -INFINITY;
#pragma unroll
        for (int nf = 0; nf < 4; ++nf)
#pragma unroll
            for (int i = 0; i < 4; ++i)
                tmax = fmaxf(tmax, s[nf][i]);
        tmax = fmaxf(tmax, __shfl_xor(tmax, 16));
        tmax = fmaxf(tmax, __shfl_xor(tmax, 32));
        if (!__all(tmax - mrow <= 8.f)) {
            float mn = fmaxf(mrow, tmax);
            float sc2 = __expf(mrow - mn);
            mrow = mn;
            lrow *= sc2;
#pragma unroll
            for (int hf = 0; hf < 4; ++hf) o[hf] *= sc2;
        }
        float rs = 0.f;
        union { ushort us[4]; uint2 u2; } pk[4];
#pragma unroll
        for (int nf = 0; nf < 4; ++nf)
#pragma unroll
            for (int i = 0; i < 4; ++i) {
                float pv = __expf(s[nf][i] - mrow);
                rs += pv;
                pk[nf].us[i] = f2bf(pv);
            }
        // 3. prefetch bias(kt+1) into accumulator (s is dead now; L1-resident)
        if (kt < 31) loadBias(kt * 64 + 64);
        rs += __shfl_xor(rs, 16);
        rs += __shfl_xor(rs, 32);
        lrow += rs;
        // 4. P -> per-wave LDS [q=c][key], packed b64 writes; wave-local
#pragma unroll
        for (int nf = 0; nf < 4; ++nf)
            *(uint2*)&Pw[c * 72 + nf * 16 + g * 4] = pk[nf].u2;
        bf16x8_t pa[2];
#pragma unroll
        for (int kk = 0; kk < 2; ++kk)
            pa[kk] = *(const bf16x8_t*)&Pw[c * 72 + kk * 32 + g * 8];
        // 5. O^T += V^T P^T
#pragma unroll
        for (int kk = 0; kk < 2; ++kk)
#pragma unroll
            for (int hf = 0; hf < 4; ++hf) {
                bf16x8_t vf = *(const bf16x8_t*)&Vs[cur][(hf * 16 + c) * 64 + ((kk * 32 + g * 8) ^ rswz)];
                o[hf] = __builtin_amdgcn_mfma_f32_16x16x32_bf16(vf, pa[kk], o[hf], 0, 0, 0);
            }
        cur ^= 1;
    }
    const float inv = 1.f / lrow;
    ushort* orow = ob + (size_t)(b * LSEQ + q0 + c) * BDIM + h * HDIM + g * 4;
#pragma unroll
    for (int hf = 0; hf < 4; ++hf) {
        ushort4 ov;
        ov.x = f2bf(o[hf][0] * inv);
        ov.y = f2bf(o[hf][1] * inv);
        ov.z = f2bf(o[hf][2] * inv);
        ov.w = f2bf(o[hf][3] * inv);
        *(ushort4*)(orow + hf * 16) = ov;
    }
}

extern "C" void kernel_launch(void* const* d_in, const int* in_sizes, int n_in,
                              void* d_out, int out_size, void* d_ws, size_t ws_size,
                              hipStream_t stream) {
    const float* x   = (const float*)d_in[0];
    const float* Wq  = (const float*)d_in[1];
    const float* Wk  = (const float*)d_in[2];
    const float* Wv  = (const float*)d_in[3];
    const float* Wo  = (const float*)d_in[4];
    const float* W1  = (const float*)d_in[5];
    const float* W2  = (const float*)d_in[6];
    const float* g1  = (const float*)d_in[7];
    const float* g2  = (const float*)d_in[8];
    const float* rel = (const float*)d_in[9];
    float* out = (float*)d_out;

    char* ws = (char*)d_ws;
    const size_t MB = 1024 * 1024;
    ushort* wqkvT = (ushort*)(ws + 0 * MB);    // 3072 x 1024 bf16 = 6MB
    ushort* woT   = (ushort*)(ws + 6 * MB);    // 2MB
    ushort* w1T   = (ushort*)(ws + 8 * MB);    // 4096 x 1024 = 8MB
    ushort* w2T   = (ushort*)(ws + 16 * MB);   // 1024 x 4096 = 8MB
    float*  btab  = (float*)(ws + 24 * MB);    // 256KB
    ushort* hbuf  = (ushort*)(ws + 25 * MB);   // 8MB: h, then attn_out, then h2
    ushort* qkvb  = (ushort*)(ws + 33 * MB);   // 4096 x 3072 = 24MB
    ushort* f1b   = (ushort*)(ws + 33 * MB);   // 32MB, reuses qkv+vT after attn
    ushort* vTb   = (ushort*)(ws + 57 * MB);   // 8MB; total 65MB
    (void)in_sizes; (void)n_in; (void)out_size; (void)ws_size;

    dim3 tb(32, 8);
    transpose_cvt<<<dim3(32, 32),  tb, 0, stream>>>(Wq, wqkvT,                1024, 1024);
    transpose_cvt<<<dim3(32, 32),  tb, 0, stream>>>(Wk, wqkvT + 1024 * 1024,  1024, 1024);
    transpose_cvt<<<dim3(32, 32),  tb, 0, stream>>>(Wv, wqkvT + 2048 * 1024,  1024, 1024);
    transpose_cvt<<<dim3(32, 32),  tb, 0, stream>>>(Wo, woT, 1024, 1024);
    transpose_cvt<<<dim3(128, 32), tb, 0, stream>>>(W1, w1T, 1024, 4096);
    transpose_cvt<<<dim3(32, 128), tb, 0, stream>>>(W2, w2T, 4096, 1024);
    bias_table_k<<<256, 256, 0, stream>>>(rel, btab);

    rmsnorm_k<<<4096, 256, 0, stream>>>(x, g1, hbuf);
    gemm_bt<0, 128, 128><<<768, 256, 0, stream>>>(hbuf, wqkvT, qkvb, nullptr, 4096, QKVN, 1024, 24);
    vtrans<<<dim3(32, 32), 256, 0, stream>>>(qkvb, vTb);
    attn_fwd<<<dim3(32, 32), 256, 0, stream>>>(qkvb, vTb, btab, hbuf);
    gemm_bt<1, 128, 64><<<512, 256, 0, stream>>>(hbuf, woT, out, x, 4096, 1024, 1024, 16);
    rmsnorm_k<<<4096, 256, 0, stream>>>(out, g2, hbuf);
    gemm_bt<2, 128, 128><<<1024, 256, 0, stream>>>(hbuf, w1T, f1b, nullptr, 4096, DFFDIM, 1024, 32);
    gemm_bt<1, 128, 64><<<512, 256, 0, stream>>>(f1b, w2T, out, out, 4096, 1024, DFFDIM, 16);
}

// Round 7
// 316.764 us; speedup vs baseline: 1.7383x; 1.0893x over previous
//
#include <hip/hip_runtime.h>
#include <hip/hip_bf16.h>
#include <math.h>

#define BDIM 1024
#define HEADS 16
#define HDIM 64
#define LSEQ 2048
#define NBATCH 2
#define DFFDIM 4096
#define QKVN 3072

typedef __bf16 bf16x8_t __attribute__((ext_vector_type(8)));
typedef float f32x4_t __attribute__((ext_vector_type(4)));

__device__ __forceinline__ ushort f2bf(float f) {
    union { __hip_bfloat16 b; ushort u; } cv;
    cv.b = __float2bfloat16(f);
    return cv.u;
}

// ---------------- transpose + fp32->bf16 convert: Wt[n][k] = bf16(W[k][n]) ----
__global__ __launch_bounds__(256) void transpose_cvt(const float* __restrict__ W,
                                                     ushort* __restrict__ Wt,
                                                     int K, int N) {
    __shared__ ushort tile[32][33];
    int bi = blockIdx.y;   // K / 32
    int bj = blockIdx.x;   // N / 32
    int tx = threadIdx.x;  // 32
    int ty = threadIdx.y;  // 8
#pragma unroll
    for (int r = 0; r < 4; ++r) {
        int krow = bi * 32 + ty + r * 8;
        int ncol = bj * 32 + tx;
        tile[ty + r * 8][tx] = f2bf(W[(size_t)krow * N + ncol]);
    }
    __syncthreads();
#pragma unroll
    for (int r = 0; r < 4; ++r) {
        int nrow = bj * 32 + ty + r * 8;
        int kcol = bi * 32 + tx;
        Wt[(size_t)nrow * K + kcol] = tile[tx][ty + r * 8];
    }
}

// ---------------- per-head V transpose: vT[(b,h)][hd][key] = V[b][key][h][hd] --
__global__ __launch_bounds__(256) void vtrans(const ushort* __restrict__ qkv,
                                              ushort* __restrict__ vT) {
    __shared__ ushort t[64][72];
    const int ktile = blockIdx.x;           // key / 64
    const int bh = blockIdx.y;
    const int b = bh >> 4, h = bh & 15;
    const int tid = threadIdx.x;
    const int r = tid >> 2;                 // 0..63
    const int c0 = (tid & 3) * 16;          // 0,16,32,48
    const ushort* src = qkv + (size_t)(b * LSEQ + ktile * 64 + r) * QKVN + 2048 + h * HDIM + c0;
    union { bf16x8_t v; ushort s[8]; } u0, u1;
    u0.v = *(const bf16x8_t*)src;
    u1.v = *(const bf16x8_t*)(src + 8);
#pragma unroll
    for (int j = 0; j < 8; ++j) { t[r][c0 + j] = u0.s[j]; t[r][c0 + 8 + j] = u1.s[j]; }
    __syncthreads();
    const int hd = tid >> 2;
    union { bf16x8_t v; ushort s[8]; } w0, w1;
#pragma unroll
    for (int j = 0; j < 8; ++j) { w0.s[j] = t[c0 + j][hd]; w1.s[j] = t[c0 + 8 + j][hd]; }
    ushort* dst = vT + (size_t)(bh * HDIM + hd) * LSEQ + ktile * 64 + c0;
    *(bf16x8_t*)dst = w0.v;
    *(bf16x8_t*)(dst + 8) = w1.v;
}

// ---------------- RMSNorm: fp32 in -> bf16 out --------------------------------
__global__ __launch_bounds__(256) void rmsnorm_k(const float* __restrict__ x,
                                                 const float* __restrict__ g,
                                                 ushort* __restrict__ out) {
    int row = blockIdx.x;
    int t = threadIdx.x;
    int w = t >> 6, l = t & 63;
    const float4 v = reinterpret_cast<const float4*>(x + (size_t)row * BDIM)[t];
    float ss = v.x * v.x + v.y * v.y + v.z * v.z + v.w * v.w;
#pragma unroll
    for (int m = 1; m <= 32; m <<= 1) ss += __shfl_xor(ss, m);
    __shared__ float wsum[4];
    if (l == 0) wsum[w] = ss;
    __syncthreads();
    float tot = wsum[0] + wsum[1] + wsum[2] + wsum[3];
    float r = rsqrtf(tot * (1.0f / BDIM) + 1e-6f);
    const float4 gv = reinterpret_cast<const float4*>(g)[t];
    ushort4 o;
    o.x = f2bf(v.x * r * gv.x);
    o.y = f2bf(v.y * r * gv.y);
    o.z = f2bf(v.z * r * gv.z);
    o.w = f2bf(v.w * r * gv.w);
    reinterpret_cast<ushort4*>(out + (size_t)row * BDIM)[t] = o;
}

// ---------------- T5 relative position bias table: btab[h][d], d = k-q+2047 ---
__global__ void bias_table_k(const float* __restrict__ rel, float* __restrict__ btab) {
    int idx = blockIdx.x * 256 + threadIdx.x;
    if (idx >= HEADS * 4095) return;
    int h = idx / 4095;
    int d = idx % 4095;
    int rp = d - 2047;                 // mem - ctx
    int bucket = rp > 0 ? 16 : 0;
    int rpa = rp < 0 ? -rp : rp;
    if (rpa < 8) {
        bucket += rpa;
    } else {
        int large = 8 + (int)(logf((float)rpa * 0.125f) * (1.0f / logf(16.0f)) * 8.0f);
        bucket += large < 15 ? large : 15;
    }
    btab[idx] = rel[bucket * HEADS + h];
}

// ---------------- bf16 GEMM, B pre-transposed (Bt is N x K), 1D grid + XCD swz
// MODE 0: bf16 out = A@B ;  MODE 1: f32 out = res + A@B ;  MODE 2: bf16 out = relu(A@B)
template <int MODE, int TM, int TN>
__global__ __launch_bounds__(256) void gemm_bt(const ushort* __restrict__ A,
                                               const ushort* __restrict__ Bt,
                                               void* Cout, const float* res,
                                               int M, int N, int K, int nbx) {
    __shared__ __align__(16) ushort As[TM * 64];
    __shared__ __align__(16) ushort Bs[TN * 64];
    constexpr int MF = TM / 32, NF = TN / 32;
    const int nwg = gridDim.x;
    const int bid = blockIdx.x;
    const int swz = (bid & 7) * (nwg >> 3) + (bid >> 3);   // nwg % 8 == 0 always
    const int bx = swz % nbx, by = swz / nbx;
    const int tid = threadIdx.x;
    const int w = tid >> 6, l = tid & 63;
    const int wm = w >> 1, wn = w & 1;
    const int rowA0 = by * TM;
    const int colB0 = bx * TN;
    const int lr = l >> 3;
    const int lc = (l & 7) * 8;
    const int c = l & 15, gq = l >> 4;
    f32x4_t acc[MF][NF] = {};

    for (int k0 = 0; k0 < K; k0 += 64) {
        __syncthreads();
#pragma unroll
        for (int i = 0; i < TM / 32; ++i) {
            int r = i * 32 + w * 8;
            __builtin_amdgcn_global_load_lds(
                (const __attribute__((address_space(1))) uint32_t*)(A + (size_t)(rowA0 + r + lr) * K + k0 + lc),
                (__attribute__((address_space(3))) uint32_t*)(&As[r * 64]), 16, 0, 0);
        }
#pragma unroll
        for (int i = 0; i < TN / 32; ++i) {
            int r = i * 32 + w * 8;
            __builtin_amdgcn_global_load_lds(
                (const __attribute__((address_space(1))) uint32_t*)(Bt + (size_t)(colB0 + r + lr) * K + k0 + lc),
                (__attribute__((address_space(3))) uint32_t*)(&Bs[r * 64]), 16, 0, 0);
        }
        __syncthreads();
#pragma unroll
        for (int kk = 0; kk < 2; ++kk) {
            bf16x8_t av[MF], bv[NF];
#pragma unroll
            for (int mf = 0; mf < MF; ++mf)
                av[mf] = *(const bf16x8_t*)&As[(wm * (TM / 2) + mf * 16 + c) * 64 + kk * 32 + gq * 8];
#pragma unroll
            for (int nf = 0; nf < NF; ++nf)
                bv[nf] = *(const bf16x8_t*)&Bs[(wn * (TN / 2) + nf * 16 + c) * 64 + kk * 32 + gq * 8];
#pragma unroll
            for (int mf = 0; mf < MF; ++mf)
#pragma unroll
                for (int nf = 0; nf < NF; ++nf)
                    acc[mf][nf] = __builtin_amdgcn_mfma_f32_16x16x32_bf16(av[mf], bv[nf], acc[mf][nf], 0, 0, 0);
        }
    }
#pragma unroll
    for (int mf = 0; mf < MF; ++mf) {
#pragma unroll
        for (int nf = 0; nf < NF; ++nf) {
#pragma unroll
            for (int i = 0; i < 4; ++i) {
                int row = rowA0 + wm * (TM / 2) + mf * 16 + gq * 4 + i;
                int col = colB0 + wn * (TN / 2) + nf * 16 + c;
                size_t idx = (size_t)row * N + col;
                float vv = acc[mf][nf][i];
                if (MODE == 0) {
                    ((ushort*)Cout)[idx] = f2bf(vv);
                } else if (MODE == 1) {
                    ((float*)Cout)[idx] = res[idx] + vv;
                } else {
                    ((ushort*)Cout)[idx] = f2bf(vv > 0.f ? vv : 0.f);
                }
            }
        }
    }
}

// ---------------- flash attention: 8-wave blocks, LDS dbuf + swizzled K/V -----
// grid: x = q-tile (L/128), y = b*H + h. block = 512 (8 waves x 16 q-rows).
// One K/V tile (64 keys) feeds 128 q-rows; staged via global_load_lds with
// pre-swizzled global source col (LDS dest linear); frag reads XOR (row&7)<<3.
// Double-buffered, 1 barrier/iter: barrier; issue stage(kt+1 -> buf^1); compute.
__global__ __launch_bounds__(512) void attn_fwd(const ushort* __restrict__ qkv,
                                                const ushort* __restrict__ vT,
                                                const float* __restrict__ btab,
                                                ushort* __restrict__ ob) {
    const int tid = threadIdx.x, w = tid >> 6, l = tid & 63;
    const int bh = blockIdx.y, b = bh >> 4, h = bh & 15;
    const int qt = blockIdx.x;
    __shared__ __align__(16) ushort Ks[2][64 * 64];    // [key][hd ^ swz]
    __shared__ __align__(16) ushort Vs[2][64 * 64];    // [hd][key ^ swz]
    __shared__ __align__(16) ushort Pl[8][16 * 72];    // per-wave P[q][key], stride 72
    const int q0 = qt * 128 + w * 16;
    const int c = l & 15, g = l >> 4;
    const size_t rowbase = (size_t)b * LSEQ * QKVN;
    const ushort* qp = qkv + rowbase + h * HDIM;
    const ushort* kp = qkv + rowbase + BDIM + h * HDIM;
    const ushort* vtp = vT + (size_t)bh * HDIM * LSEQ;
    // staging: 512 threads cover the 64x64 tile in one pass; lane's LDS slot is
    // row sr = tid>>3, 16B chunk (l&7); global source col pre-swizzled.
    const int sr = tid >> 3;                     // 0..63
    const int scs = ((l & 7) ^ (l >> 3)) * 8;    // swizzled source col (ushorts)
    // bias for (key, q=q0+c): btq4[key0 + nf*16 + i]
    const float* btq4 = btab + h * 4095 + 2047 - (q0 + c) + g * 4;

    bf16x8_t aq[2];  // B-operand: Q[q0+c][kk*32 + g*8 + j]
#pragma unroll
    for (int kk = 0; kk < 2; ++kk)
        aq[kk] = *(const bf16x8_t*)(qp + (size_t)(q0 + c) * QKVN + kk * 32 + g * 8);

    float mrow = -INFINITY, lrow = 0.f;
    f32x4_t o[4] = {};   // O^T[hd = hf*16 + g*4 + i][q0+c]
    f32x4_t s[4];        // S^T[key0 + nf*16 + g*4 + i][q0+c]

    auto stage = [&](int buf, int key0) {
        __builtin_amdgcn_global_load_lds(
            (const __attribute__((address_space(1))) uint32_t*)(kp + (size_t)(key0 + sr) * QKVN + scs),
            (__attribute__((address_space(3))) uint32_t*)(&Ks[buf][(w * 8) * 64]), 16, 0, 0);
        __builtin_amdgcn_global_load_lds(
            (const __attribute__((address_space(1))) uint32_t*)(vtp + (size_t)sr * LSEQ + key0 + scs),
            (__attribute__((address_space(3))) uint32_t*)(&Vs[buf][(w * 8) * 64]), 16, 0, 0);
    };
    auto loadBias = [&](int key0) {
#pragma unroll
        for (int nf = 0; nf < 4; ++nf)
#pragma unroll
            for (int i = 0; i < 4; ++i)
                s[nf][i] = btq4[key0 + nf * 16 + i];
    };

    stage(0, 0);
    loadBias(0);
    int cur = 0;

    ushort* Pw = Pl[w];
    const int rswz = (c & 7) << 3;   // read-side XOR for rows nf*16+c / hf*16+c
    for (int kt = 0; kt < 32; ++kt) {
        __syncthreads();   // buf[cur] staged (vmcnt drained at barrier); buf[cur^1] free
        // issue next tile's stage NOW -> latency hidden under compute below
        if (kt < 31) stage(cur ^ 1, kt * 64 + 64);
        // 1. S^T = bias + K Q^T
#pragma unroll
        for (int kk = 0; kk < 2; ++kk)
#pragma unroll
            for (int nf = 0; nf < 4; ++nf) {
                bf16x8_t kf = *(const bf16x8_t*)&Ks[cur][(nf * 16 + c) * 64 + ((kk * 32 + g * 8) ^ rswz)];
                s[nf] = __builtin_amdgcn_mfma_f32_16x16x32_bf16(kf, aq[kk], s[nf], 0, 0, 0);
            }
        // 2. softmax: in-lane max over 16 + 2 cross-lane shfl
        float tmax = -INFINITY;
#pragma unroll
        for (int nf = 0; nf < 4; ++nf)
#pragma unroll
            for (int i = 0; i < 4; ++i)
                tmax = fmaxf(tmax, s[nf][i]);
        tmax = fmaxf(tmax, __shfl_xor(tmax, 16));
        tmax = fmaxf(tmax, __shfl_xor(tmax, 32));
        if (!__all(tmax - mrow <= 8.f)) {
            float mn = fmaxf(mrow, tmax);
            float sc2 = __expf(mrow - mn);
            mrow = mn;
            lrow *= sc2;
#pragma unroll
            for (int hf = 0; hf < 4; ++hf) o[hf] *= sc2;
        }
        float rs = 0.f;
        union { ushort us[4]; uint2 u2; } pk[4];
#pragma unroll
        for (int nf = 0; nf < 4; ++nf)
#pragma unroll
            for (int i = 0; i < 4; ++i) {
                float pv = __expf(s[nf][i] - mrow);
                rs += pv;
                pk[nf].us[i] = f2bf(pv);
            }
        // 3. prefetch bias(kt+1) into accumulator (s is dead now; L1-resident)
        if (kt < 31) loadBias(kt * 64 + 64);
        rs += __shfl_xor(rs, 16);
        rs += __shfl_xor(rs, 32);
        lrow += rs;
        // 4. P -> per-wave LDS [q=c][key], packed b64 writes; wave-local
#pragma unroll
        for (int nf = 0; nf < 4; ++nf)
            *(uint2*)&Pw[c * 72 + nf * 16 + g * 4] = pk[nf].u2;
        bf16x8_t pa[2];
#pragma unroll
        for (int kk = 0; kk < 2; ++kk)
            pa[kk] = *(const bf16x8_t*)&Pw[c * 72 + kk * 32 + g * 8];
        // 5. O^T += V^T P^T
#pragma unroll
        for (int kk = 0; kk < 2; ++kk)
#pragma unroll
            for (int hf = 0; hf < 4; ++hf) {
                bf16x8_t vf = *(const bf16x8_t*)&Vs[cur][(hf * 16 + c) * 64 + ((kk * 32 + g * 8) ^ rswz)];
                o[hf] = __builtin_amdgcn_mfma_f32_16x16x32_bf16(vf, pa[kk], o[hf], 0, 0, 0);
            }
        cur ^= 1;
    }
    const float inv = 1.f / lrow;
    ushort* orow = ob + (size_t)(b * LSEQ + q0 + c) * BDIM + h * HDIM + g * 4;
#pragma unroll
    for (int hf = 0; hf < 4; ++hf) {
        ushort4 ov;
        ov.x = f2bf(o[hf][0] * inv);
        ov.y = f2bf(o[hf][1] * inv);
        ov.z = f2bf(o[hf][2] * inv);
        ov.w = f2bf(o[hf][3] * inv);
        *(ushort4*)(orow + hf * 16) = ov;
    }
}

extern "C" void kernel_launch(void* const* d_in, const int* in_sizes, int n_in,
                              void* d_out, int out_size, void* d_ws, size_t ws_size,
                              hipStream_t stream) {
    const float* x   = (const float*)d_in[0];
    const float* Wq  = (const float*)d_in[1];
    const float* Wk  = (const float*)d_in[2];
    const float* Wv  = (const float*)d_in[3];
    const float* Wo  = (const float*)d_in[4];
    const float* W1  = (const float*)d_in[5];
    const float* W2  = (const float*)d_in[6];
    const float* g1  = (const float*)d_in[7];
    const float* g2  = (const float*)d_in[8];
    const float* rel = (const float*)d_in[9];
    float* out = (float*)d_out;

    char* ws = (char*)d_ws;
    const size_t MB = 1024 * 1024;
    ushort* wqkvT = (ushort*)(ws + 0 * MB);    // 3072 x 1024 bf16 = 6MB
    ushort* woT   = (ushort*)(ws + 6 * MB);    // 2MB
    ushort* w1T   = (ushort*)(ws + 8 * MB);    // 4096 x 1024 = 8MB
    ushort* w2T   = (ushort*)(ws + 16 * MB);   // 1024 x 4096 = 8MB
    float*  btab  = (float*)(ws + 24 * MB);    // 256KB
    ushort* hbuf  = (ushort*)(ws + 25 * MB);   // 8MB: h, then attn_out, then h2
    ushort* qkvb  = (ushort*)(ws + 33 * MB);   // 4096 x 3072 = 24MB
    ushort* f1b   = (ushort*)(ws + 33 * MB);   // 32MB, reuses qkv+vT after attn
    ushort* vTb   = (ushort*)(ws + 57 * MB);   // 8MB; total 65MB
    (void)in_sizes; (void)n_in; (void)out_size; (void)ws_size;

    dim3 tb(32, 8);
    transpose_cvt<<<dim3(32, 32),  tb, 0, stream>>>(Wq, wqkvT,                1024, 1024);
    transpose_cvt<<<dim3(32, 32),  tb, 0, stream>>>(Wk, wqkvT + 1024 * 1024,  1024, 1024);
    transpose_cvt<<<dim3(32, 32),  tb, 0, stream>>>(Wv, wqkvT + 2048 * 1024,  1024, 1024);
    transpose_cvt<<<dim3(32, 32),  tb, 0, stream>>>(Wo, woT, 1024, 1024);
    transpose_cvt<<<dim3(128, 32), tb, 0, stream>>>(W1, w1T, 1024, 4096);
    transpose_cvt<<<dim3(32, 128), tb, 0, stream>>>(W2, w2T, 4096, 1024);
    bias_table_k<<<256, 256, 0, stream>>>(rel, btab);

    rmsnorm_k<<<4096, 256, 0, stream>>>(x, g1, hbuf);
    gemm_bt<0, 128, 128><<<768, 256, 0, stream>>>(hbuf, wqkvT, qkvb, nullptr, 4096, QKVN, 1024, 24);
    vtrans<<<dim3(32, 32), 256, 0, stream>>>(qkvb, vTb);
    attn_fwd<<<dim3(16, 32), 512, 0, stream>>>(qkvb, vTb, btab, hbuf);
    gemm_bt<1, 128, 64><<<512, 256, 0, stream>>>(hbuf, woT, out, x, 4096, 1024, 1024, 16);
    rmsnorm_k<<<4096, 256, 0, stream>>>(out, g2, hbuf);
    gemm_bt<2, 128, 128><<<1024, 256, 0, stream>>>(hbuf, w1T, f1b, nullptr, 4096, DFFDIM, 1024, 32);
    gemm_bt<1, 128, 64><<<512, 256, 0, stream>>>(f1b, w2T, out, out, 4096, 1024, DFFDIM, 16);
}